// Round 14
// baseline (1283.502 us; speedup 1.0000x reference)
//
#include <hip/hip_runtime.h>
#include <math.h>

#define NMAPS 16
#define DIN 512
#define DOUT 128
#define QD 64
#define VCOL 160  // floats per V column: 8 t-slices x 20 (conflict-free b128)
#define TST 20

typedef __attribute__((ext_vector_type(8))) short bf16x8;  // 8 bf16 (4 VGPR)
typedef __attribute__((ext_vector_type(4))) float f32x4;
typedef __attribute__((ext_vector_type(2))) float f32x2;

// Packed fp32 FMA (VOP3P): bitwise-identical to two scalar fmaf's.
__device__ __forceinline__ f32x2 pkfma(f32x2 a, f32x2 b, f32x2 c) {
  f32x2 d;
  asm("v_pk_fma_f32 %0, %1, %2, %3" : "=v"(d) : "v"(a), "v"(b), "v"(c));
  return d;
}

// bf16 split helpers (RNE). x = bf2f(hi) + bf2f(lo) + O(2^-18 |x|).
__device__ __forceinline__ unsigned short f2bf(float x) {
  unsigned int u = __float_as_uint(x);
  return (unsigned short)((u + 0x7FFFu + ((u >> 16) & 1u)) >> 16);
}
__device__ __forceinline__ float bf2f(unsigned short h) {
  return __uint_as_float(((unsigned int)h) << 16);
}

// DPP helpers (VALU pipe).
__device__ __forceinline__ float qxor1(float x) {
  return __int_as_float(__builtin_amdgcn_update_dpp(
      0, __float_as_int(x), 0xB1, 0xF, 0xF, true));
}
__device__ __forceinline__ float qxor2(float x) {
  return __int_as_float(__builtin_amdgcn_update_dpp(
      0, __float_as_int(x), 0x4E, 0xF, 0xF, true));
}
__device__ __forceinline__ float hmirror(float x) {  // row_half_mirror
  return __int_as_float(__builtin_amdgcn_update_dpp(
      0, __float_as_int(x), 0x141, 0xF, 0xF, true));
}
// All-VALU butterfly sum over the 8-lane group (validated R13).
__device__ __forceinline__ float groupSum8(float x) {
  x += qxor1(x);
  x += qxor2(x);
  x += hmirror(x);
  return x;
}

// slarfg sign convention (LAPACK) — unchanged since R4.
__device__ __forceinline__ void make_tau(float xn2, float alpha, float& tau,
                                         float& invs) {
  if (xn2 == 0.f) { tau = 0.f; invs = 0.f; }
  else {
    float mag = sqrtf(alpha * alpha + xn2);
    float beta = (alpha >= 0.f) ? -mag : mag;
    tau = (beta - alpha) / beta;
    invs = 1.f / (alpha - beta);
  }
}

__device__ __forceinline__ float pk_dot8(const f32x2 (&x)[8],
                                         const f32x2 (&y)[8]) {
  f32x2 pa = {0.f, 0.f}, pb = {0.f, 0.f};
#pragma unroll
  for (int i = 0; i < 4; ++i) {
    pa = pkfma(x[2 * i], y[2 * i], pa);
    pb = pkfma(x[2 * i + 1], y[2 * i + 1], pb);
  }
  return (pa.x + pa.y) + (pb.x + pb.y);
}

__device__ __forceinline__ float norm_gt8(const f32x2 (&a2)[8], const int t,
                                          const int piv) {
  float ss[4] = {0.f, 0.f, 0.f, 0.f};
#pragma unroll
  for (int q = 0; q < 4; ++q)
#pragma unroll
    for (int kk = 0; kk < 4; ++kk) {
      int k = 4 * q + kk;
      int r = t + 8 * k;
      float av = a2[k >> 1][k & 1];
      if (r > piv) ss[q] = fmaf(av, av, ss[q]);
    }
  return ((ss[0] + ss[1]) + ss[2]) + ss[3];
}

template <bool SCALE>
__device__ __forceinline__ void publish_col8(f32x2 (&a2)[8], const int t,
                                             const int piv, const float invs,
                                             float* __restrict__ Vrow) {
#pragma unroll
  for (int k4 = 0; k4 < 4; ++k4) {
    float4 v4;
    float* vv = (float*)&v4;
#pragma unroll
    for (int e = 0; e < 4; ++e) {
      int k = 4 * k4 + e;
      int r = t + 8 * k;
      float av = a2[k >> 1][k & 1];
      float nv;
      if (r > piv) {
        if (SCALE) { av *= invs; a2[k >> 1][k & 1] = av; }
        nv = av;
      } else nv = (r == piv) ? 1.f : 0.f;
      vv[e] = nv;
    }
    *(float4*)&Vrow[4 * k4] = v4;
  }
}

__device__ __forceinline__ void load_v8(f32x2 (&vr2)[8],
                                        const float* __restrict__ Vrow) {
#pragma unroll
  for (int k4 = 0; k4 < 4; ++k4) {
    float4 v4 = *(const float4*)&Vrow[4 * k4];
    vr2[2 * k4] = (f32x2){v4.x, v4.y};
    vr2[2 * k4 + 1] = (f32x2){v4.z, v4.w};
  }
}

// ---------------- pre-split kernels (write d_ws; fragment-order layout) -------
__global__ __launch_bounds__(256) void presplit_w(const float* __restrict__ W,
                                                  unsigned short* __restrict__ Wp) {
  int id = blockIdx.x * 256 + threadIdx.x;
  int row = id & 127;
  int fg = (id >> 7) & 3;
  int mc = id >> 9;
  int mm = mc >> 4, ch = mc & 15;
  const float* src = W + ((size_t)mm * DOUT + row) * DIN + ch * 32 + fg * 8;
  bf16x8 hi, lo;
  unsigned short* hp = (unsigned short*)&hi;
  unsigned short* lp = (unsigned short*)&lo;
#pragma unroll
  for (int e = 0; e < 8; ++e) {
    float v = src[e];
    unsigned short h = f2bf(v);
    hp[e] = h;
    lp[e] = f2bf(v - bf2f(h));
  }
  unsigned short* dst = Wp + (size_t)mc * 8192 + (fg * 128 + row) * 8;
  *(bf16x8*)dst = hi;
  *(bf16x8*)(dst + 4096) = lo;
}

__global__ __launch_bounds__(256) void presplit_x(const float* __restrict__ X,
                                                  unsigned short* __restrict__ Xp) {
  int id = blockIdx.x * 256 + threadIdx.x;
  int col = id & 63;
  int fg = (id >> 6) & 3;
  int bc = id >> 8;
  int bb = bc >> 4, ch = bc & 15;
  const float* src = X + ((size_t)bb * DIN + ch * 32 + fg * 8) * QD + col;
  bf16x8 hi, lo;
  unsigned short* hp = (unsigned short*)&hi;
  unsigned short* lp = (unsigned short*)&lo;
#pragma unroll
  for (int e = 0; e < 8; ++e) {
    float v = src[(size_t)e * QD];
    unsigned short h = f2bf(v);
    hp[e] = h;
    lp[e] = f2bf(v - bf2f(h));
  }
  unsigned short* dst = Xp + (size_t)bc * 4096 + (fg * 64 + col) * 8;
  *(bf16x8*)dst = hi;
  *(bf16x8*)(dst + 2048) = lo;
}

union USh {
  float Buf[64][68];     // 17408 B (handoff + store)
  float Vall[QD][VCOL];  // 40960 B (persistent V, [col][t*20+k])
};

// One block (512 thr = 8 waves) per matrix (m,b).
// 2a: R13 sequential sgeqr2 (1 barrier/step, publish-ahead) into persistent Vall.
// S: one batch phase computes intra-block Gram S[p][di][dj] (di>dj).
// 2b: BARRIER-FREE blocked org2r — per wave, blocks p = w..0, each: 8 uniform
//   dots -> 28 serial Gram corrections -> 8 deferred axpys. Block == wave, so
//   all V/S/Tau reads are wave-uniform broadcasts (no R11 conflict trap).
template <bool PRE>
__global__ __launch_bounds__(512, 6) void frmap_qr(
    const float* __restrict__ X, const float* __restrict__ W,
    float* __restrict__ out, const unsigned short* __restrict__ Wp,
    const unsigned short* __restrict__ Xp) {
  __shared__ __align__(16) USh U;
  __shared__ float S[8][8][8];
  __shared__ float Tau[QD];

  const int tid = threadIdx.x;
  const int l = tid & 63;
  const int w = __builtin_amdgcn_readfirstlane(tid >> 6);  // wave 0..7
  const int rg = w >> 1;  // GEMM row-group
  const int cg = w & 1;   // GEMM col-group
  const int c = tid >> 3; // QR column 0..63 (c>>3 == w)
  const int t = tid & 7;  // QR row class (rows t+8k)
  const int fr = l & 15;
  const int fg = l >> 4;

  const int bid = blockIdx.x;  // m*256 + b
  const int m = bid >> 8;
  const int b = bid & 255;
  const float* Xb = X + (size_t)b * (DIN * QD);
  const float* Wm = W + (size_t)m * (DOUT * DIN);

  f32x4 acc[2][2];
#pragma unroll
  for (int tr = 0; tr < 2; ++tr)
#pragma unroll
    for (int tc = 0; tc < 2; ++tc)
      acc[tr][tc] = (f32x4){0.f, 0.f, 0.f, 0.f};

  if constexpr (PRE) {
    const char* wsrc = (const char*)Wp + (size_t)(m * 16) * 16384;
    const char* xsrc = (const char*)Xp + (size_t)(b * 16) * 8192;
    const int woff = (fg * 128 + 32 * rg + fr) * 16;
    const int xoff = (fg * 64 + 32 * cg + fr) * 16;
    for (int ch = 0; ch < 16; ++ch) {
      bf16x8 ah0 = *(const bf16x8*)(wsrc + woff);
      bf16x8 al0 = *(const bf16x8*)(wsrc + 8192 + woff);
      bf16x8 ah1 = *(const bf16x8*)(wsrc + woff + 256);
      bf16x8 al1 = *(const bf16x8*)(wsrc + 8192 + woff + 256);
      bf16x8 bh0 = *(const bf16x8*)(xsrc + xoff);
      bf16x8 bl0 = *(const bf16x8*)(xsrc + 4096 + xoff);
      bf16x8 bh1 = *(const bf16x8*)(xsrc + xoff + 256);
      bf16x8 bl1 = *(const bf16x8*)(xsrc + 4096 + xoff + 256);
      acc[0][0] = __builtin_amdgcn_mfma_f32_16x16x32_bf16(ah0, bh0, acc[0][0], 0, 0, 0);
      acc[0][0] = __builtin_amdgcn_mfma_f32_16x16x32_bf16(ah0, bl0, acc[0][0], 0, 0, 0);
      acc[0][0] = __builtin_amdgcn_mfma_f32_16x16x32_bf16(al0, bh0, acc[0][0], 0, 0, 0);
      acc[0][1] = __builtin_amdgcn_mfma_f32_16x16x32_bf16(ah0, bh1, acc[0][1], 0, 0, 0);
      acc[0][1] = __builtin_amdgcn_mfma_f32_16x16x32_bf16(ah0, bl1, acc[0][1], 0, 0, 0);
      acc[0][1] = __builtin_amdgcn_mfma_f32_16x16x32_bf16(al0, bh1, acc[0][1], 0, 0, 0);
      acc[1][0] = __builtin_amdgcn_mfma_f32_16x16x32_bf16(ah1, bh0, acc[1][0], 0, 0, 0);
      acc[1][0] = __builtin_amdgcn_mfma_f32_16x16x32_bf16(ah1, bl0, acc[1][0], 0, 0, 0);
      acc[1][0] = __builtin_amdgcn_mfma_f32_16x16x32_bf16(al1, bh0, acc[1][0], 0, 0, 0);
      acc[1][1] = __builtin_amdgcn_mfma_f32_16x16x32_bf16(ah1, bh1, acc[1][1], 0, 0, 0);
      acc[1][1] = __builtin_amdgcn_mfma_f32_16x16x32_bf16(ah1, bl1, acc[1][1], 0, 0, 0);
      acc[1][1] = __builtin_amdgcn_mfma_f32_16x16x32_bf16(al1, bh1, acc[1][1], 0, 0, 0);
      wsrc += 16384;
      xsrc += 8192;
    }
  } else {
    for (int ch = 0; ch < 16; ++ch) {
      int kc = ch * 32;
      bf16x8 ah[2], al[2], bh[2], bl[2];
#pragma unroll
      for (int tr = 0; tr < 2; ++tr) {
        const float* ws = Wm + (size_t)(32 * rg + 16 * tr + fr) * DIN + kc + 8 * fg;
        float4 v0 = *(const float4*)ws;
        float4 v1 = *(const float4*)(ws + 4);
        float p[8] = {v0.x, v0.y, v0.z, v0.w, v1.x, v1.y, v1.z, v1.w};
        unsigned short* hp = (unsigned short*)&ah[tr];
        unsigned short* lp = (unsigned short*)&al[tr];
#pragma unroll
        for (int e = 0; e < 8; ++e) {
          unsigned short h = f2bf(p[e]);
          hp[e] = h;
          lp[e] = f2bf(p[e] - bf2f(h));
        }
      }
#pragma unroll
      for (int tc = 0; tc < 2; ++tc) {
        const float* xs = Xb + (size_t)(kc + 8 * fg) * QD + 32 * cg + 16 * tc + fr;
        unsigned short* hp = (unsigned short*)&bh[tc];
        unsigned short* lp = (unsigned short*)&bl[tc];
#pragma unroll
        for (int e = 0; e < 8; ++e) {
          float v = xs[(size_t)e * QD];
          unsigned short h = f2bf(v);
          hp[e] = h;
          lp[e] = f2bf(v - bf2f(h));
        }
      }
#pragma unroll
      for (int tr = 0; tr < 2; ++tr)
#pragma unroll
        for (int tc = 0; tc < 2; ++tc) {
          acc[tr][tc] = __builtin_amdgcn_mfma_f32_16x16x32_bf16(ah[tr], bh[tc], acc[tr][tc], 0, 0, 0);
          acc[tr][tc] = __builtin_amdgcn_mfma_f32_16x16x32_bf16(ah[tr], bl[tc], acc[tr][tc], 0, 0, 0);
          acc[tr][tc] = __builtin_amdgcn_mfma_f32_16x16x32_bf16(al[tr], bh[tc], acc[tr][tc], 0, 0, 0);
        }
    }
  }

  // ---------------- Phase 1.5: acc -> Buf -> QR ownership
  f32x2 a2[8];
  if (rg < 2) {
#pragma unroll
    for (int tr = 0; tr < 2; ++tr)
#pragma unroll
      for (int tc = 0; tc < 2; ++tc)
#pragma unroll
        for (int v = 0; v < 4; ++v)
          U.Buf[32 * rg + 16 * tr + 4 * fg + v][32 * cg + 16 * tc + fr] = acc[tr][tc][v];
  }
  __syncthreads();
#pragma unroll
  for (int k = 0; k < 8; ++k) a2[k >> 1][k & 1] = U.Buf[t + 8 * k][c];
  __syncthreads();
  if (rg >= 2) {
#pragma unroll
    for (int tr = 0; tr < 2; ++tr)
#pragma unroll
      for (int tc = 0; tc < 2; ++tc)
#pragma unroll
        for (int v = 0; v < 4; ++v)
          U.Buf[32 * (rg - 2) + 16 * tr + 4 * fg + v][32 * cg + 16 * tc + fr] = acc[tr][tc][v];
  }
  __syncthreads();
#pragma unroll
  for (int k = 8; k < 16; ++k) a2[k >> 1][k & 1] = U.Buf[t + 8 * k - 64][c];
  __syncthreads();  // ALIAS FENCE: Buf reads done before Vall (union) writes

  // ---------------- prologue: group c==0 makes tau0/invs0, scales, publishes
  if (c == 0) {
    float myalpha = 0.f;
#pragma unroll
    for (int k = 0; k < 16; ++k)
      if (t + 8 * k == 0) myalpha = a2[k >> 1][k & 1];
    float xn2 = groupSum8(norm_gt8(a2, t, 0));
    float alpha = groupSum8(myalpha);
    float tau, invs;
    make_tau(xn2, alpha, tau, invs);
    if (t == 0) Tau[0] = tau;
    publish_col8<true>(a2, t, 0, invs, &U.Vall[0][t * TST]);
  }
  __syncthreads();  // B0

  // ---------------- Phase 2a: sgeqr2 (R13, V into persistent Vall)
  for (int j = 0; j < QD - 1; ++j) {
    if (c > j) {
      float taul = Tau[j];
      f32x2 vr2[8];
      load_v8(vr2, &U.Vall[j][t * TST]);  // uniform col -> broadcast
      float wv = taul * groupSum8(pk_dot8(vr2, a2));
      f32x2 nw2 = {-wv, -wv};
#pragma unroll
      for (int i = 0; i < 8; ++i) a2[i] = pkfma(nw2, vr2[i], a2[i]);
      if (c == j + 1) {
        float myalpha = 0.f;
#pragma unroll
        for (int k = 0; k < 16; ++k)
          if (t + 8 * k == j + 1) myalpha = a2[k >> 1][k & 1];
        float xn2 = groupSum8(norm_gt8(a2, t, j + 1));
        float alpha = groupSum8(myalpha);
        float tau, invs;
        make_tau(xn2, alpha, tau, invs);
        if (t == 0) Tau[j + 1] = tau;
        publish_col8<true>(a2, t, j + 1, invs, &U.Vall[j + 1][t * TST]);
      }
    }
    __syncthreads();
  }

  // ---------------- S phase: intra-block Gram S[p][di][dj] = v_{8p+di}.v_{8p+dj}
  // 224 pairs over 64 groups (<=4 each); non-uniform col reads (one-time cost).
#pragma unroll
  for (int e = 0; e < 4; ++e) {
    int q = c + 64 * e;  // group-uniform
    if (q < 224) {
      int p = q / 28;
      int r = q - 28 * p;
      int di = (r < 1) ? 1 : (r < 3) ? 2 : (r < 6) ? 3
               : (r < 10) ? 4 : (r < 15) ? 5 : (r < 21) ? 6 : 7;
      int dj = r - di * (di - 1) / 2;
      f32x2 vi[8], vj[8];
      load_v8(vi, &U.Vall[8 * p + di][t * TST]);
      load_v8(vj, &U.Vall[8 * p + dj][t * TST]);
      float s = groupSum8(pk_dot8(vi, vj));
      if (t == 0) S[p][di][dj] = s;
    }
  }
  __syncthreads();  // S visible; Vall/Tau already fenced

  // ---------------- Phase 2b: BARRIER-FREE blocked org2r
  {
    float tauc = Tau[c];
#pragma unroll
    for (int k = 0; k < 16; ++k) {  // formation (local): u = e_c - tau_c v_c
      int r = t + 8 * k;
      float val = a2[k >> 1][k & 1];
      float nv;
      if (r == c) nv = 1.f - tauc;
      else if (r < c) nv = 0.f;
      else nv = -tauc * val;
      a2[k >> 1][k & 1] = nv;
    }
    for (int p = w; p >= 0; --p) {  // wave-uniform block loop (c>>3 == w)
      float d[8];
#pragma unroll
      for (int il = 0; il < 8; ++il) {  // 8 independent dots, uniform loads
        int i = 8 * p + il;
        f32x2 vr2[8];
        load_v8(vr2, &U.Vall[i][t * TST]);
        float dd = groupSum8(pk_dot8(vr2, a2));
        d[il] = (i < c) ? dd : 0.f;     // predicate: only reflectors i < c
      }
      float wvv[8];
#pragma unroll
      for (int il = 7; il >= 0; --il) {  // serial Gram corrections (28 FMA)
        float wl = Tau[8 * p + il] * d[il];
        wvv[il] = wl;
#pragma unroll
        for (int il2 = 0; il2 < il; ++il2)
          d[il2] = fmaf(-wl, S[p][il][il2], d[il2]);
      }
#pragma unroll
      for (int il = 0; il < 8; ++il) {  // deferred axpys (linear in a)
        f32x2 vr2[8];
        load_v8(vr2, &U.Vall[8 * p + il][t * TST]);
        f32x2 nw2 = {-wvv[il], -wvv[il]};
#pragma unroll
        for (int i2 = 0; i2 < 8; ++i2) a2[i2] = pkfma(nw2, vr2[i2], a2[i2]);
      }
    }
  }
  __syncthreads();  // ALIAS FENCE: all Vall reads done before Buf (union) writes

  // ---------------- Phase 3: store via Buf (256B-coalesced)
  float* O = out + (size_t)bid * (DOUT * QD);
#pragma unroll
  for (int k = 0; k < 8; ++k) U.Buf[t + 8 * k][c] = a2[k >> 1][k & 1];
  __syncthreads();
#pragma unroll
  for (int i = 0; i < 8; ++i) {
    int r = 8 * w + i;
    O[r * QD + l] = U.Buf[r][l];
  }
  __syncthreads();
#pragma unroll
  for (int k = 8; k < 16; ++k) U.Buf[t + 8 * k - 64][c] = a2[k >> 1][k & 1];
  __syncthreads();
#pragma unroll
  for (int i = 0; i < 8; ++i) {
    int r = 8 * w + i;
    O[(64 + r) * QD + l] = U.Buf[r][l];
  }
}

extern "C" void kernel_launch(void* const* d_in, const int* in_sizes, int n_in,
                              void* d_out, int out_size, void* d_ws, size_t ws_size,
                              hipStream_t stream) {
  const float* X = (const float*)d_in[0];   // (256, 512, 64) fp32
  const float* W = (const float*)d_in[1];   // (16, 128, 512) fp32
  float* out = (float*)d_out;               // (4096, 128, 64) fp32

  const size_t needW = (size_t)NMAPS * 16 * 16384;  // 4 MiB
  const size_t needX = (size_t)256 * 16 * 8192;     // 32 MiB
  if (ws_size >= needW + needX) {
    unsigned short* Wp = (unsigned short*)d_ws;
    unsigned short* Xp = (unsigned short*)((char*)d_ws + needW);
    presplit_w<<<512, 256, 0, stream>>>(W, Wp);
    presplit_x<<<4096, 256, 0, stream>>>(X, Xp);
    frmap_qr<true><<<NMAPS * 256, 512, 0, stream>>>(X, W, out, Wp, Xp);
  } else {
    frmap_qr<false><<<NMAPS * 256, 512, 0, stream>>>(X, W, out, nullptr, nullptr);
  }
}

// Round 16
// 379.837 us; speedup vs baseline: 3.3791x; 3.3791x over previous
//
#include <hip/hip_runtime.h>
#include <math.h>

#define NMAPS 16
#define DIN 512
#define DOUT 128
#define QD 64

typedef __attribute__((ext_vector_type(8))) short bf16x8;  // 8 bf16 (4 VGPR)
typedef __attribute__((ext_vector_type(4))) float f32x4;
typedef __attribute__((ext_vector_type(2))) float f32x2;

// Packed fp32 FMA (VOP3P): bitwise-identical to two scalar fmaf's.
__device__ __forceinline__ f32x2 pkfma(f32x2 a, f32x2 b, f32x2 c) {
  f32x2 d;
  asm("v_pk_fma_f32 %0, %1, %2, %3" : "=v"(d) : "v"(a), "v"(b), "v"(c));
  return d;
}

// bf16 split helpers (RNE). x = bf2f(hi) + bf2f(lo) + O(2^-18 |x|).
__device__ __forceinline__ unsigned short f2bf(float x) {
  unsigned int u = __float_as_uint(x);
  return (unsigned short)((u + 0x7FFFu + ((u >> 16) & 1u)) >> 16);
}
__device__ __forceinline__ float bf2f(unsigned short h) {
  return __uint_as_float(((unsigned int)h) << 16);
}

// DPP helpers (VALU pipe).
__device__ __forceinline__ float qxor1(float x) {
  return __int_as_float(__builtin_amdgcn_update_dpp(
      0, __float_as_int(x), 0xB1, 0xF, 0xF, true));
}
__device__ __forceinline__ float qxor2(float x) {
  return __int_as_float(__builtin_amdgcn_update_dpp(
      0, __float_as_int(x), 0x4E, 0xF, 0xF, true));
}
__device__ __forceinline__ float hmirror(float x) {  // row_half_mirror
  return __int_as_float(__builtin_amdgcn_update_dpp(
      0, __float_as_int(x), 0x141, 0xF, 0xF, true));
}
// All-VALU butterfly sum over the 8-lane group (validated R13).
__device__ __forceinline__ float groupSum8(float x) {
  x += qxor1(x);
  x += qxor2(x);
  x += hmirror(x);
  return x;
}

// slarfg sign convention (LAPACK) — unchanged since R4.
__device__ __forceinline__ void make_tau(float xn2, float alpha, float& tau,
                                         float& invs) {
  if (xn2 == 0.f) { tau = 0.f; invs = 0.f; }
  else {
    float mag = sqrtf(alpha * alpha + xn2);
    float beta = (alpha >= 0.f) ? -mag : mag;
    tau = (beta - alpha) / beta;
    invs = 1.f / (alpha - beta);
  }
}

__device__ __forceinline__ float pk_dot8(const f32x2 (&x)[8],
                                         const f32x2 (&y)[8]) {
  f32x2 pa = {0.f, 0.f}, pb = {0.f, 0.f};
#pragma unroll
  for (int i = 0; i < 4; ++i) {
    pa = pkfma(x[2 * i], y[2 * i], pa);
    pb = pkfma(x[2 * i + 1], y[2 * i + 1], pb);
  }
  return (pa.x + pa.y) + (pb.x + pb.y);
}

__device__ __forceinline__ float norm_gt8(const f32x2 (&a2)[8], const int t,
                                          const int piv) {
  float ss[4] = {0.f, 0.f, 0.f, 0.f};
#pragma unroll
  for (int q = 0; q < 4; ++q)
#pragma unroll
    for (int kk = 0; kk < 4; ++kk) {
      int k = 4 * q + kk;
      int r = t + 8 * k;
      float av = a2[k >> 1][k & 1];
      if (r > piv) ss[q] = fmaf(av, av, ss[q]);
    }
  return ((ss[0] + ss[1]) + ss[2]) + ss[3];
}

template <bool SCALE>
__device__ __forceinline__ void publish_col8(f32x2 (&a2)[8], const int t,
                                             const int piv, const float invs,
                                             float* __restrict__ Vrow) {
#pragma unroll
  for (int k4 = 0; k4 < 4; ++k4) {
    float4 v4;
    float* vv = (float*)&v4;
#pragma unroll
    for (int e = 0; e < 4; ++e) {
      int k = 4 * k4 + e;
      int r = t + 8 * k;
      float av = a2[k >> 1][k & 1];
      float nv;
      if (r > piv) {
        if (SCALE) { av *= invs; a2[k >> 1][k & 1] = av; }
        nv = av;
      } else nv = (r == piv) ? 1.f : 0.f;
      vv[e] = nv;
    }
    *(float4*)&Vrow[4 * k4] = v4;
  }
}

__device__ __forceinline__ void load_v8(f32x2 (&vr2)[8],
                                        const float* __restrict__ Vrow) {
#pragma unroll
  for (int k4 = 0; k4 < 4; ++k4) {
    float4 v4 = *(const float4*)&Vrow[4 * k4];
    vr2[2 * k4] = (f32x2){v4.x, v4.y};
    vr2[2 * k4 + 1] = (f32x2){v4.z, v4.w};
  }
}

// ---------------- pre-split kernels (write d_ws; fragment-order layout) -------
__global__ __launch_bounds__(256) void presplit_w(const float* __restrict__ W,
                                                  unsigned short* __restrict__ Wp) {
  int id = blockIdx.x * 256 + threadIdx.x;
  int row = id & 127;
  int fg = (id >> 7) & 3;
  int mc = id >> 9;
  int mm = mc >> 4, ch = mc & 15;
  const float* src = W + ((size_t)mm * DOUT + row) * DIN + ch * 32 + fg * 8;
  bf16x8 hi, lo;
  unsigned short* hp = (unsigned short*)&hi;
  unsigned short* lp = (unsigned short*)&lo;
#pragma unroll
  for (int e = 0; e < 8; ++e) {
    float v = src[e];
    unsigned short h = f2bf(v);
    hp[e] = h;
    lp[e] = f2bf(v - bf2f(h));
  }
  unsigned short* dst = Wp + (size_t)mc * 8192 + (fg * 128 + row) * 8;
  *(bf16x8*)dst = hi;
  *(bf16x8*)(dst + 4096) = lo;
}

__global__ __launch_bounds__(256) void presplit_x(const float* __restrict__ X,
                                                  unsigned short* __restrict__ Xp) {
  int id = blockIdx.x * 256 + threadIdx.x;
  int col = id & 63;
  int fg = (id >> 6) & 3;
  int bc = id >> 8;
  int bb = bc >> 4, ch = bc & 15;
  const float* src = X + ((size_t)bb * DIN + ch * 32 + fg * 8) * QD + col;
  bf16x8 hi, lo;
  unsigned short* hp = (unsigned short*)&hi;
  unsigned short* lp = (unsigned short*)&lo;
#pragma unroll
  for (int e = 0; e < 8; ++e) {
    float v = src[(size_t)e * QD];
    unsigned short h = f2bf(v);
    hp[e] = h;
    lp[e] = f2bf(v - bf2f(h));
  }
  unsigned short* dst = Xp + (size_t)bc * 4096 + (fg * 64 + col) * 8;
  *(bf16x8*)dst = hi;
  *(bf16x8*)(dst + 2048) = lo;
}

// One block (512 thr = 8 waves) per matrix (m,b). R13 structure (best passing):
// - GEMM: direct-fragment MFMA from pre-split d_ws arrays (no LDS staging)
// - QR state packed as f32x2[8]; hot dot/update via v_pk_fma_f32
// - 2a: sequential sgeqr2, 1 barrier/step, publish-ahead, Vq double buffer
// - 2b: sequential sorg2r, 1 barrier/step, publish-ahead
// (R11/R14/R15 2b-restructures all failed: conflicts / spill / unexplained.)
template <bool PRE>
__global__ __launch_bounds__(512, 6) void frmap_qr(
    const float* __restrict__ X, const float* __restrict__ W,
    float* __restrict__ out, const unsigned short* __restrict__ Wp,
    const unsigned short* __restrict__ Xp) {
  __shared__ __align__(16) float Buf[64][68];   // stride 68: 2-way max (free)
  __shared__ __align__(16) float Vq[2][8][20];  // conflict-free b128
  __shared__ float Tau[QD];

  const int tid = threadIdx.x;
  const int l = tid & 63;
  const int w = __builtin_amdgcn_readfirstlane(tid >> 6);  // wave 0..7
  const int rg = w >> 1;  // GEMM row-group
  const int cg = w & 1;   // GEMM col-group
  const int c = tid >> 3; // QR column 0..63
  const int t = tid & 7;  // QR row class (rows t+8k)
  const int fr = l & 15;
  const int fg = l >> 4;

  const int bid = blockIdx.x;  // m*256 + b
  const int m = bid >> 8;
  const int b = bid & 255;
  const float* Xb = X + (size_t)b * (DIN * QD);
  const float* Wm = W + (size_t)m * (DOUT * DIN);

  f32x4 acc[2][2];
#pragma unroll
  for (int tr = 0; tr < 2; ++tr)
#pragma unroll
    for (int tc = 0; tc < 2; ++tc)
      acc[tr][tc] = (f32x4){0.f, 0.f, 0.f, 0.f};

  if constexpr (PRE) {
    const char* wsrc = (const char*)Wp + (size_t)(m * 16) * 16384;
    const char* xsrc = (const char*)Xp + (size_t)(b * 16) * 8192;
    const int woff = (fg * 128 + 32 * rg + fr) * 16;
    const int xoff = (fg * 64 + 32 * cg + fr) * 16;
    for (int ch = 0; ch < 16; ++ch) {
      bf16x8 ah0 = *(const bf16x8*)(wsrc + woff);
      bf16x8 al0 = *(const bf16x8*)(wsrc + 8192 + woff);
      bf16x8 ah1 = *(const bf16x8*)(wsrc + woff + 256);
      bf16x8 al1 = *(const bf16x8*)(wsrc + 8192 + woff + 256);
      bf16x8 bh0 = *(const bf16x8*)(xsrc + xoff);
      bf16x8 bl0 = *(const bf16x8*)(xsrc + 4096 + xoff);
      bf16x8 bh1 = *(const bf16x8*)(xsrc + xoff + 256);
      bf16x8 bl1 = *(const bf16x8*)(xsrc + 4096 + xoff + 256);
      acc[0][0] = __builtin_amdgcn_mfma_f32_16x16x32_bf16(ah0, bh0, acc[0][0], 0, 0, 0);
      acc[0][0] = __builtin_amdgcn_mfma_f32_16x16x32_bf16(ah0, bl0, acc[0][0], 0, 0, 0);
      acc[0][0] = __builtin_amdgcn_mfma_f32_16x16x32_bf16(al0, bh0, acc[0][0], 0, 0, 0);
      acc[0][1] = __builtin_amdgcn_mfma_f32_16x16x32_bf16(ah0, bh1, acc[0][1], 0, 0, 0);
      acc[0][1] = __builtin_amdgcn_mfma_f32_16x16x32_bf16(ah0, bl1, acc[0][1], 0, 0, 0);
      acc[0][1] = __builtin_amdgcn_mfma_f32_16x16x32_bf16(al0, bh1, acc[0][1], 0, 0, 0);
      acc[1][0] = __builtin_amdgcn_mfma_f32_16x16x32_bf16(ah1, bh0, acc[1][0], 0, 0, 0);
      acc[1][0] = __builtin_amdgcn_mfma_f32_16x16x32_bf16(ah1, bl0, acc[1][0], 0, 0, 0);
      acc[1][0] = __builtin_amdgcn_mfma_f32_16x16x32_bf16(al1, bh0, acc[1][0], 0, 0, 0);
      acc[1][1] = __builtin_amdgcn_mfma_f32_16x16x32_bf16(ah1, bh1, acc[1][1], 0, 0, 0);
      acc[1][1] = __builtin_amdgcn_mfma_f32_16x16x32_bf16(ah1, bl1, acc[1][1], 0, 0, 0);
      acc[1][1] = __builtin_amdgcn_mfma_f32_16x16x32_bf16(al1, bh1, acc[1][1], 0, 0, 0);
      wsrc += 16384;
      xsrc += 8192;
    }
  } else {
    for (int ch = 0; ch < 16; ++ch) {
      int kc = ch * 32;
      bf16x8 ah[2], al[2], bh[2], bl[2];
#pragma unroll
      for (int tr = 0; tr < 2; ++tr) {
        const float* ws = Wm + (size_t)(32 * rg + 16 * tr + fr) * DIN + kc + 8 * fg;
        float4 v0 = *(const float4*)ws;
        float4 v1 = *(const float4*)(ws + 4);
        float p[8] = {v0.x, v0.y, v0.z, v0.w, v1.x, v1.y, v1.z, v1.w};
        unsigned short* hp = (unsigned short*)&ah[tr];
        unsigned short* lp = (unsigned short*)&al[tr];
#pragma unroll
        for (int e = 0; e < 8; ++e) {
          unsigned short h = f2bf(p[e]);
          hp[e] = h;
          lp[e] = f2bf(p[e] - bf2f(h));
        }
      }
#pragma unroll
      for (int tc = 0; tc < 2; ++tc) {
        const float* xs = Xb + (size_t)(kc + 8 * fg) * QD + 32 * cg + 16 * tc + fr;
        unsigned short* hp = (unsigned short*)&bh[tc];
        unsigned short* lp = (unsigned short*)&bl[tc];
#pragma unroll
        for (int e = 0; e < 8; ++e) {
          float v = xs[(size_t)e * QD];
          unsigned short h = f2bf(v);
          hp[e] = h;
          lp[e] = f2bf(v - bf2f(h));
        }
      }
#pragma unroll
      for (int tr = 0; tr < 2; ++tr)
#pragma unroll
        for (int tc = 0; tc < 2; ++tc) {
          acc[tr][tc] = __builtin_amdgcn_mfma_f32_16x16x32_bf16(ah[tr], bh[tc], acc[tr][tc], 0, 0, 0);
          acc[tr][tc] = __builtin_amdgcn_mfma_f32_16x16x32_bf16(ah[tr], bl[tc], acc[tr][tc], 0, 0, 0);
          acc[tr][tc] = __builtin_amdgcn_mfma_f32_16x16x32_bf16(al[tr], bh[tc], acc[tr][tc], 0, 0, 0);
        }
    }
  }

  // ---------------- Phase 1.5: acc -> Buf -> QR ownership
  f32x2 a2[8];
  if (rg < 2) {
#pragma unroll
    for (int tr = 0; tr < 2; ++tr)
#pragma unroll
      for (int tc = 0; tc < 2; ++tc)
#pragma unroll
        for (int v = 0; v < 4; ++v)
          Buf[32 * rg + 16 * tr + 4 * fg + v][32 * cg + 16 * tc + fr] = acc[tr][tc][v];
  }
  __syncthreads();
#pragma unroll
  for (int k = 0; k < 8; ++k) a2[k >> 1][k & 1] = Buf[t + 8 * k][c];
  __syncthreads();
  if (rg >= 2) {
#pragma unroll
    for (int tr = 0; tr < 2; ++tr)
#pragma unroll
      for (int tc = 0; tc < 2; ++tc)
#pragma unroll
        for (int v = 0; v < 4; ++v)
          Buf[32 * (rg - 2) + 16 * tr + 4 * fg + v][32 * cg + 16 * tc + fr] = acc[tr][tc][v];
  }
  __syncthreads();
#pragma unroll
  for (int k = 8; k < 16; ++k) a2[k >> 1][k & 1] = Buf[t + 8 * k - 64][c];

  // ---------------- prologue: group c==0 makes tau0/invs0, scales, publishes
  if (c == 0) {
    float myalpha = 0.f;
#pragma unroll
    for (int k = 0; k < 16; ++k)
      if (t + 8 * k == 0) myalpha = a2[k >> 1][k & 1];
    float xn2 = groupSum8(norm_gt8(a2, t, 0));
    float alpha = groupSum8(myalpha);
    float tau, invs;
    make_tau(xn2, alpha, tau, invs);
    if (t == 0) Tau[0] = tau;
    publish_col8<true>(a2, t, 0, invs, &Vq[0][t][0]);
  }
  __syncthreads();  // B0: V_0 / Tau[0] visible

  // ---------------- Phase 2a: sgeqr2 (1 barrier/step, publish-ahead)
  for (int j = 0; j < QD - 1; ++j) {
    if (c > j) {
      float taul = Tau[j];
      f32x2 vr2[8];
      load_v8(vr2, &Vq[j & 1][t][0]);
      float wv = taul * groupSum8(pk_dot8(vr2, a2));
      f32x2 nw2 = {-wv, -wv};
#pragma unroll
      for (int i = 0; i < 8; ++i) a2[i] = pkfma(nw2, vr2[i], a2[i]);
      if (c == j + 1) {  // tail: next pivot's tau/scale/publish
        float myalpha = 0.f;
#pragma unroll
        for (int k = 0; k < 16; ++k)
          if (t + 8 * k == j + 1) myalpha = a2[k >> 1][k & 1];
        float xn2 = groupSum8(norm_gt8(a2, t, j + 1));
        float alpha = groupSum8(myalpha);
        float tau, invs;
        make_tau(xn2, alpha, tau, invs);
        if (t == 0) Tau[j + 1] = tau;
        publish_col8<true>(a2, t, j + 1, invs, &Vq[(j + 1) & 1][t][0]);
      }
    }
    __syncthreads();  // fences V_{j+1}, Tau[j+1], Vq buffer reuse
  }

  __syncthreads();  // phase boundary

  // ---------------- Phase 2b: sorg2r (1 barrier/step, publish-ahead)
  for (int i = QD - 1; i >= 0; --i) {
    if (c > i) {
      float taul = Tau[i];
      f32x2 vr2[8];
      load_v8(vr2, &Vq[i & 1][t][0]);
      float wv = taul * groupSum8(pk_dot8(vr2, a2));
      f32x2 nw2 = {-wv, -wv};
#pragma unroll
      for (int q = 0; q < 8; ++q) a2[q] = pkfma(nw2, vr2[q], a2[q]);
    } else if (c == i) {  // own column: 0 / 1-tau / -tau*v
      float taul = Tau[i];
#pragma unroll
      for (int k = 0; k < 16; ++k) {
        int r = t + 8 * k;
        float val = a2[k >> 1][k & 1];
        float nv;
        if (r == i) nv = 1.f - taul;
        else if (r < i) nv = 0.f;
        else nv = -taul * val;
        a2[k >> 1][k & 1] = nv;
      }
    } else if (c == i - 1) {  // idle group publishes V_{i-1}
      publish_col8<false>(a2, t, i - 1, 0.f, &Vq[(i - 1) & 1][t][0]);
    }
    if (i) __syncthreads();
  }

  // ---------------- Phase 3: store via Buf (256B-coalesced)
  float* O = out + (size_t)bid * (DOUT * QD);
#pragma unroll
  for (int k = 0; k < 8; ++k) Buf[t + 8 * k][c] = a2[k >> 1][k & 1];
  __syncthreads();
#pragma unroll
  for (int i = 0; i < 8; ++i) {
    int r = 8 * w + i;
    O[r * QD + l] = Buf[r][l];
  }
  __syncthreads();
#pragma unroll
  for (int k = 8; k < 16; ++k) Buf[t + 8 * k - 64][c] = a2[k >> 1][k & 1];
  __syncthreads();
#pragma unroll
  for (int i = 0; i < 8; ++i) {
    int r = 8 * w + i;
    O[(64 + r) * QD + l] = Buf[r][l];
  }
}

extern "C" void kernel_launch(void* const* d_in, const int* in_sizes, int n_in,
                              void* d_out, int out_size, void* d_ws, size_t ws_size,
                              hipStream_t stream) {
  const float* X = (const float*)d_in[0];   // (256, 512, 64) fp32
  const float* W = (const float*)d_in[1];   // (16, 128, 512) fp32
  float* out = (float*)d_out;               // (4096, 128, 64) fp32

  const size_t needW = (size_t)NMAPS * 16 * 16384;  // 4 MiB
  const size_t needX = (size_t)256 * 16 * 8192;     // 32 MiB
  if (ws_size >= needW + needX) {
    unsigned short* Wp = (unsigned short*)d_ws;
    unsigned short* Xp = (unsigned short*)((char*)d_ws + needW);
    presplit_w<<<512, 256, 0, stream>>>(W, Wp);
    presplit_x<<<4096, 256, 0, stream>>>(X, Xp);
    frmap_qr<true><<<NMAPS * 256, 512, 0, stream>>>(X, W, out, Wp, Xp);
  } else {
    frmap_qr<false><<<NMAPS * 256, 512, 0, stream>>>(X, W, out, nullptr, nullptr);
  }
}

// Round 17
// 360.960 us; speedup vs baseline: 3.5558x; 1.0523x over previous
//
#include <hip/hip_runtime.h>
#include <math.h>

#define NMAPS 16
#define DIN 512
#define DOUT 128
#define QD 64

typedef __attribute__((ext_vector_type(8))) short bf16x8;  // 8 bf16 (4 VGPR)
typedef __attribute__((ext_vector_type(4))) float f32x4;
typedef __attribute__((ext_vector_type(2))) float f32x2;

// Packed fp32 FMA (VOP3P): bitwise-identical to two scalar fmaf's.
__device__ __forceinline__ f32x2 pkfma(f32x2 a, f32x2 b, f32x2 c) {
  f32x2 d;
  asm("v_pk_fma_f32 %0, %1, %2, %3" : "=v"(d) : "v"(a), "v"(b), "v"(c));
  return d;
}

// Fast scalar ops (~1 ulp): off the div_scale/div_fixup sequences that sit on
// the tail group's convoy-critical path 127x per block.
__device__ __forceinline__ float frcp(float x) {
  float r;
  asm("v_rcp_f32 %0, %1" : "=v"(r) : "v"(x));
  return r;
}
__device__ __forceinline__ float fsqrt_fast(float x) {
  float r;
  asm("v_sqrt_f32 %0, %1" : "=v"(r) : "v"(x));
  return r;
}

// bf16 split helpers (RNE). x = bf2f(hi) + bf2f(lo) + O(2^-18 |x|).
__device__ __forceinline__ unsigned short f2bf(float x) {
  unsigned int u = __float_as_uint(x);
  return (unsigned short)((u + 0x7FFFu + ((u >> 16) & 1u)) >> 16);
}
__device__ __forceinline__ float bf2f(unsigned short h) {
  return __uint_as_float(((unsigned int)h) << 16);
}

// DPP helpers (VALU pipe).
__device__ __forceinline__ float qxor1(float x) {
  return __int_as_float(__builtin_amdgcn_update_dpp(
      0, __float_as_int(x), 0xB1, 0xF, 0xF, true));
}
__device__ __forceinline__ float qxor2(float x) {
  return __int_as_float(__builtin_amdgcn_update_dpp(
      0, __float_as_int(x), 0x4E, 0xF, 0xF, true));
}
__device__ __forceinline__ float hmirror(float x) {  // row_half_mirror
  return __int_as_float(__builtin_amdgcn_update_dpp(
      0, __float_as_int(x), 0x141, 0xF, 0xF, true));
}
// All-VALU butterfly sum over the 8-lane group (validated R13).
__device__ __forceinline__ float groupSum8(float x) {
  x += qxor1(x);
  x += qxor2(x);
  x += hmirror(x);
  return x;
}

// slarfg sign convention (LAPACK); divides/sqrt replaced by 1-ulp fast ops
// (tau/invs perturbed ~1e-7 rel — negligible vs the 9.1e-3 threshold).
__device__ __forceinline__ void make_tau(float xn2, float alpha, float& tau,
                                         float& invs) {
  if (xn2 == 0.f) { tau = 0.f; invs = 0.f; }
  else {
    float mag = fsqrt_fast(fmaf(alpha, alpha, xn2));
    float beta = (alpha >= 0.f) ? -mag : mag;
    tau = (beta - alpha) * frcp(beta);
    invs = frcp(alpha - beta);
  }
}

__device__ __forceinline__ float pk_dot8(const f32x2 (&x)[8],
                                         const f32x2 (&y)[8]) {
  f32x2 pa = {0.f, 0.f}, pb = {0.f, 0.f};
#pragma unroll
  for (int i = 0; i < 4; ++i) {
    pa = pkfma(x[2 * i], y[2 * i], pa);
    pb = pkfma(x[2 * i + 1], y[2 * i + 1], pb);
  }
  return (pa.x + pa.y) + (pb.x + pb.y);
}

__device__ __forceinline__ float norm_gt8(const f32x2 (&a2)[8], const int t,
                                          const int piv) {
  float ss[4] = {0.f, 0.f, 0.f, 0.f};
#pragma unroll
  for (int q = 0; q < 4; ++q)
#pragma unroll
    for (int kk = 0; kk < 4; ++kk) {
      int k = 4 * q + kk;
      int r = t + 8 * k;
      float av = a2[k >> 1][k & 1];
      if (r > piv) ss[q] = fmaf(av, av, ss[q]);
    }
  return ((ss[0] + ss[1]) + ss[2]) + ss[3];
}

template <bool SCALE>
__device__ __forceinline__ void publish_col8(f32x2 (&a2)[8], const int t,
                                             const int piv, const float invs,
                                             float* __restrict__ Vrow) {
#pragma unroll
  for (int k4 = 0; k4 < 4; ++k4) {
    float4 v4;
    float* vv = (float*)&v4;
#pragma unroll
    for (int e = 0; e < 4; ++e) {
      int k = 4 * k4 + e;
      int r = t + 8 * k;
      float av = a2[k >> 1][k & 1];
      float nv;
      if (r > piv) {
        if (SCALE) { av *= invs; a2[k >> 1][k & 1] = av; }
        nv = av;
      } else nv = (r == piv) ? 1.f : 0.f;
      vv[e] = nv;
    }
    *(float4*)&Vrow[4 * k4] = v4;
  }
}

__device__ __forceinline__ void load_v8(f32x2 (&vr2)[8],
                                        const float* __restrict__ Vrow) {
#pragma unroll
  for (int k4 = 0; k4 < 4; ++k4) {
    float4 v4 = *(const float4*)&Vrow[4 * k4];
    vr2[2 * k4] = (f32x2){v4.x, v4.y};
    vr2[2 * k4 + 1] = (f32x2){v4.z, v4.w};
  }
}

// ---------------- pre-split kernels (write d_ws; fragment-order layout) -------
__global__ __launch_bounds__(256) void presplit_w(const float* __restrict__ W,
                                                  unsigned short* __restrict__ Wp) {
  int id = blockIdx.x * 256 + threadIdx.x;
  int row = id & 127;
  int fg = (id >> 7) & 3;
  int mc = id >> 9;
  int mm = mc >> 4, ch = mc & 15;
  const float* src = W + ((size_t)mm * DOUT + row) * DIN + ch * 32 + fg * 8;
  bf16x8 hi, lo;
  unsigned short* hp = (unsigned short*)&hi;
  unsigned short* lp = (unsigned short*)&lo;
#pragma unroll
  for (int e = 0; e < 8; ++e) {
    float v = src[e];
    unsigned short h = f2bf(v);
    hp[e] = h;
    lp[e] = f2bf(v - bf2f(h));
  }
  unsigned short* dst = Wp + (size_t)mc * 8192 + (fg * 128 + row) * 8;
  *(bf16x8*)dst = hi;
  *(bf16x8*)(dst + 4096) = lo;
}

__global__ __launch_bounds__(256) void presplit_x(const float* __restrict__ X,
                                                  unsigned short* __restrict__ Xp) {
  int id = blockIdx.x * 256 + threadIdx.x;
  int col = id & 63;
  int fg = (id >> 6) & 3;
  int bc = id >> 8;
  int bb = bc >> 4, ch = bc & 15;
  const float* src = X + ((size_t)bb * DIN + ch * 32 + fg * 8) * QD + col;
  bf16x8 hi, lo;
  unsigned short* hp = (unsigned short*)&hi;
  unsigned short* lp = (unsigned short*)&lo;
#pragma unroll
  for (int e = 0; e < 8; ++e) {
    float v = src[(size_t)e * QD];
    unsigned short h = f2bf(v);
    hp[e] = h;
    lp[e] = f2bf(v - bf2f(h));
  }
  unsigned short* dst = Xp + (size_t)bc * 4096 + (fg * 64 + col) * 8;
  *(bf16x8*)dst = hi;
  *(bf16x8*)(dst + 2048) = lo;
}

// One block (512 thr = 8 waves) per matrix (m,b). R13 structure (best passing)
// + fast-math tail (rcp/sqrt) + redundant 2a->2b boundary barrier removed.
template <bool PRE>
__global__ __launch_bounds__(512, 6) void frmap_qr(
    const float* __restrict__ X, const float* __restrict__ W,
    float* __restrict__ out, const unsigned short* __restrict__ Wp,
    const unsigned short* __restrict__ Xp) {
  __shared__ __align__(16) float Buf[64][68];   // stride 68: 2-way max (free)
  __shared__ __align__(16) float Vq[2][8][20];  // conflict-free b128
  __shared__ float Tau[QD];

  const int tid = threadIdx.x;
  const int l = tid & 63;
  const int w = __builtin_amdgcn_readfirstlane(tid >> 6);  // wave 0..7
  const int rg = w >> 1;  // GEMM row-group
  const int cg = w & 1;   // GEMM col-group
  const int c = tid >> 3; // QR column 0..63
  const int t = tid & 7;  // QR row class (rows t+8k)
  const int fr = l & 15;
  const int fg = l >> 4;

  const int bid = blockIdx.x;  // m*256 + b
  const int m = bid >> 8;
  const int b = bid & 255;
  const float* Xb = X + (size_t)b * (DIN * QD);
  const float* Wm = W + (size_t)m * (DOUT * DIN);

  f32x4 acc[2][2];
#pragma unroll
  for (int tr = 0; tr < 2; ++tr)
#pragma unroll
    for (int tc = 0; tc < 2; ++tc)
      acc[tr][tc] = (f32x4){0.f, 0.f, 0.f, 0.f};

  if constexpr (PRE) {
    const char* wsrc = (const char*)Wp + (size_t)(m * 16) * 16384;
    const char* xsrc = (const char*)Xp + (size_t)(b * 16) * 8192;
    const int woff = (fg * 128 + 32 * rg + fr) * 16;
    const int xoff = (fg * 64 + 32 * cg + fr) * 16;
    for (int ch = 0; ch < 16; ++ch) {
      bf16x8 ah0 = *(const bf16x8*)(wsrc + woff);
      bf16x8 al0 = *(const bf16x8*)(wsrc + 8192 + woff);
      bf16x8 ah1 = *(const bf16x8*)(wsrc + woff + 256);
      bf16x8 al1 = *(const bf16x8*)(wsrc + 8192 + woff + 256);
      bf16x8 bh0 = *(const bf16x8*)(xsrc + xoff);
      bf16x8 bl0 = *(const bf16x8*)(xsrc + 4096 + xoff);
      bf16x8 bh1 = *(const bf16x8*)(xsrc + xoff + 256);
      bf16x8 bl1 = *(const bf16x8*)(xsrc + 4096 + xoff + 256);
      acc[0][0] = __builtin_amdgcn_mfma_f32_16x16x32_bf16(ah0, bh0, acc[0][0], 0, 0, 0);
      acc[0][0] = __builtin_amdgcn_mfma_f32_16x16x32_bf16(ah0, bl0, acc[0][0], 0, 0, 0);
      acc[0][0] = __builtin_amdgcn_mfma_f32_16x16x32_bf16(al0, bh0, acc[0][0], 0, 0, 0);
      acc[0][1] = __builtin_amdgcn_mfma_f32_16x16x32_bf16(ah0, bh1, acc[0][1], 0, 0, 0);
      acc[0][1] = __builtin_amdgcn_mfma_f32_16x16x32_bf16(ah0, bl1, acc[0][1], 0, 0, 0);
      acc[0][1] = __builtin_amdgcn_mfma_f32_16x16x32_bf16(al0, bh1, acc[0][1], 0, 0, 0);
      acc[1][0] = __builtin_amdgcn_mfma_f32_16x16x32_bf16(ah1, bh0, acc[1][0], 0, 0, 0);
      acc[1][0] = __builtin_amdgcn_mfma_f32_16x16x32_bf16(ah1, bl0, acc[1][0], 0, 0, 0);
      acc[1][0] = __builtin_amdgcn_mfma_f32_16x16x32_bf16(al1, bh0, acc[1][0], 0, 0, 0);
      acc[1][1] = __builtin_amdgcn_mfma_f32_16x16x32_bf16(ah1, bh1, acc[1][1], 0, 0, 0);
      acc[1][1] = __builtin_amdgcn_mfma_f32_16x16x32_bf16(ah1, bl1, acc[1][1], 0, 0, 0);
      acc[1][1] = __builtin_amdgcn_mfma_f32_16x16x32_bf16(al1, bh1, acc[1][1], 0, 0, 0);
      wsrc += 16384;
      xsrc += 8192;
    }
  } else {
    for (int ch = 0; ch < 16; ++ch) {
      int kc = ch * 32;
      bf16x8 ah[2], al[2], bh[2], bl[2];
#pragma unroll
      for (int tr = 0; tr < 2; ++tr) {
        const float* ws = Wm + (size_t)(32 * rg + 16 * tr + fr) * DIN + kc + 8 * fg;
        float4 v0 = *(const float4*)ws;
        float4 v1 = *(const float4*)(ws + 4);
        float p[8] = {v0.x, v0.y, v0.z, v0.w, v1.x, v1.y, v1.z, v1.w};
        unsigned short* hp = (unsigned short*)&ah[tr];
        unsigned short* lp = (unsigned short*)&al[tr];
#pragma unroll
        for (int e = 0; e < 8; ++e) {
          unsigned short h = f2bf(p[e]);
          hp[e] = h;
          lp[e] = f2bf(p[e] - bf2f(h));
        }
      }
#pragma unroll
      for (int tc = 0; tc < 2; ++tc) {
        const float* xs = Xb + (size_t)(kc + 8 * fg) * QD + 32 * cg + 16 * tc + fr;
        unsigned short* hp = (unsigned short*)&bh[tc];
        unsigned short* lp = (unsigned short*)&bl[tc];
#pragma unroll
        for (int e = 0; e < 8; ++e) {
          float v = xs[(size_t)e * QD];
          unsigned short h = f2bf(v);
          hp[e] = h;
          lp[e] = f2bf(v - bf2f(h));
        }
      }
#pragma unroll
      for (int tr = 0; tr < 2; ++tr)
#pragma unroll
        for (int tc = 0; tc < 2; ++tc) {
          acc[tr][tc] = __builtin_amdgcn_mfma_f32_16x16x32_bf16(ah[tr], bh[tc], acc[tr][tc], 0, 0, 0);
          acc[tr][tc] = __builtin_amdgcn_mfma_f32_16x16x32_bf16(ah[tr], bl[tc], acc[tr][tc], 0, 0, 0);
          acc[tr][tc] = __builtin_amdgcn_mfma_f32_16x16x32_bf16(al[tr], bh[tc], acc[tr][tc], 0, 0, 0);
        }
    }
  }

  // ---------------- Phase 1.5: acc -> Buf -> QR ownership
  f32x2 a2[8];
  if (rg < 2) {
#pragma unroll
    for (int tr = 0; tr < 2; ++tr)
#pragma unroll
      for (int tc = 0; tc < 2; ++tc)
#pragma unroll
        for (int v = 0; v < 4; ++v)
          Buf[32 * rg + 16 * tr + 4 * fg + v][32 * cg + 16 * tc + fr] = acc[tr][tc][v];
  }
  __syncthreads();
#pragma unroll
  for (int k = 0; k < 8; ++k) a2[k >> 1][k & 1] = Buf[t + 8 * k][c];
  __syncthreads();
  if (rg >= 2) {
#pragma unroll
    for (int tr = 0; tr < 2; ++tr)
#pragma unroll
      for (int tc = 0; tc < 2; ++tc)
#pragma unroll
        for (int v = 0; v < 4; ++v)
          Buf[32 * (rg - 2) + 16 * tr + 4 * fg + v][32 * cg + 16 * tc + fr] = acc[tr][tc][v];
  }
  __syncthreads();
#pragma unroll
  for (int k = 8; k < 16; ++k) a2[k >> 1][k & 1] = Buf[t + 8 * k - 64][c];

  // ---------------- prologue: group c==0 makes tau0/invs0, scales, publishes
  if (c == 0) {
    float myalpha = 0.f;
#pragma unroll
    for (int k = 0; k < 16; ++k)
      if (t + 8 * k == 0) myalpha = a2[k >> 1][k & 1];
    float xn2 = groupSum8(norm_gt8(a2, t, 0));
    float alpha = groupSum8(myalpha);
    float tau, invs;
    make_tau(xn2, alpha, tau, invs);
    if (t == 0) Tau[0] = tau;
    publish_col8<true>(a2, t, 0, invs, &Vq[0][t][0]);
  }
  __syncthreads();  // B0: V_0 / Tau[0] visible

  // ---------------- Phase 2a: sgeqr2 (1 barrier/step, publish-ahead)
  for (int j = 0; j < QD - 1; ++j) {
    if (c > j) {
      float taul = Tau[j];
      f32x2 vr2[8];
      load_v8(vr2, &Vq[j & 1][t][0]);
      float wv = taul * groupSum8(pk_dot8(vr2, a2));
      f32x2 nw2 = {-wv, -wv};
#pragma unroll
      for (int i = 0; i < 8; ++i) a2[i] = pkfma(nw2, vr2[i], a2[i]);
      if (c == j + 1) {  // tail: next pivot's tau/scale/publish
        float myalpha = 0.f;
#pragma unroll
        for (int k = 0; k < 16; ++k)
          if (t + 8 * k == j + 1) myalpha = a2[k >> 1][k & 1];
        float xn2 = groupSum8(norm_gt8(a2, t, j + 1));
        float alpha = groupSum8(myalpha);
        float tau, invs;
        make_tau(xn2, alpha, tau, invs);
        if (t == 0) Tau[j + 1] = tau;
        publish_col8<true>(a2, t, j + 1, invs, &Vq[(j + 1) & 1][t][0]);
      }
    }
    __syncthreads();  // fences V_{j+1}, Tau[j+1], Vq buffer reuse
  }
  // (phase-boundary barrier removed: j=62's end barrier already fences V_63 /
  //  Tau; the i=63 step's Vq[0] publish is WAR across that same barrier.)

  // ---------------- Phase 2b: sorg2r (1 barrier/step, publish-ahead)
  for (int i = QD - 1; i >= 0; --i) {
    if (c > i) {
      float taul = Tau[i];
      f32x2 vr2[8];
      load_v8(vr2, &Vq[i & 1][t][0]);
      float wv = taul * groupSum8(pk_dot8(vr2, a2));
      f32x2 nw2 = {-wv, -wv};
#pragma unroll
      for (int q = 0; q < 8; ++q) a2[q] = pkfma(nw2, vr2[q], a2[q]);
    } else if (c == i) {  // own column: 0 / 1-tau / -tau*v
      float taul = Tau[i];
#pragma unroll
      for (int k = 0; k < 16; ++k) {
        int r = t + 8 * k;
        float val = a2[k >> 1][k & 1];
        float nv;
        if (r == i) nv = 1.f - taul;
        else if (r < i) nv = 0.f;
        else nv = -taul * val;
        a2[k >> 1][k & 1] = nv;
      }
    } else if (c == i - 1) {  // idle group publishes V_{i-1}
      publish_col8<false>(a2, t, i - 1, 0.f, &Vq[(i - 1) & 1][t][0]);
    }
    if (i) __syncthreads();
  }

  // ---------------- Phase 3: store via Buf (256B-coalesced)
  float* O = out + (size_t)bid * (DOUT * QD);
#pragma unroll
  for (int k = 0; k < 8; ++k) Buf[t + 8 * k][c] = a2[k >> 1][k & 1];
  __syncthreads();
#pragma unroll
  for (int i = 0; i < 8; ++i) {
    int r = 8 * w + i;
    O[r * QD + l] = Buf[r][l];
  }
  __syncthreads();
#pragma unroll
  for (int k = 8; k < 16; ++k) Buf[t + 8 * k - 64][c] = a2[k >> 1][k & 1];
  __syncthreads();
#pragma unroll
  for (int i = 0; i < 8; ++i) {
    int r = 8 * w + i;
    O[(64 + r) * QD + l] = Buf[r][l];
  }
}

extern "C" void kernel_launch(void* const* d_in, const int* in_sizes, int n_in,
                              void* d_out, int out_size, void* d_ws, size_t ws_size,
                              hipStream_t stream) {
  const float* X = (const float*)d_in[0];   // (256, 512, 64) fp32
  const float* W = (const float*)d_in[1];   // (16, 128, 512) fp32
  float* out = (float*)d_out;               // (4096, 128, 64) fp32

  const size_t needW = (size_t)NMAPS * 16 * 16384;  // 4 MiB
  const size_t needX = (size_t)256 * 16 * 8192;     // 32 MiB
  if (ws_size >= needW + needX) {
    unsigned short* Wp = (unsigned short*)d_ws;
    unsigned short* Xp = (unsigned short*)((char*)d_ws + needW);
    presplit_w<<<512, 256, 0, stream>>>(W, Wp);
    presplit_x<<<4096, 256, 0, stream>>>(X, Xp);
    frmap_qr<true><<<NMAPS * 256, 512, 0, stream>>>(X, W, out, Wp, Xp);
  } else {
    frmap_qr<false><<<NMAPS * 256, 512, 0, stream>>>(X, W, out, nullptr, nullptr);
  }
}

// Round 18
// 355.276 us; speedup vs baseline: 3.6127x; 1.0160x over previous
//
#include <hip/hip_runtime.h>
#include <math.h>

#define NMAPS 16
#define DIN 512
#define DOUT 128
#define QD 64
#define TST 20   // per-t sub-stride in a V column (8x20 = 160 floats/col)

typedef __attribute__((ext_vector_type(8))) short bf16x8;  // 8 bf16 (4 VGPR)
typedef __attribute__((ext_vector_type(4))) float f32x4;
typedef __attribute__((ext_vector_type(2))) float f32x2;

// Packed fp32 FMA (VOP3P): bitwise-identical to two scalar fmaf's.
__device__ __forceinline__ f32x2 pkfma(f32x2 a, f32x2 b, f32x2 c) {
  f32x2 d;
  asm("v_pk_fma_f32 %0, %1, %2, %3" : "=v"(d) : "v"(a), "v"(b), "v"(c));
  return d;
}

// Fast scalar ops (~1 ulp), validated R17.
__device__ __forceinline__ float frcp(float x) {
  float r;
  asm("v_rcp_f32 %0, %1" : "=v"(r) : "v"(x));
  return r;
}
__device__ __forceinline__ float fsqrt_fast(float x) {
  float r;
  asm("v_sqrt_f32 %0, %1" : "=v"(r) : "v"(x));
  return r;
}

// bf16 split helpers (RNE). x = bf2f(hi) + bf2f(lo) + O(2^-18 |x|).
__device__ __forceinline__ unsigned short f2bf(float x) {
  unsigned int u = __float_as_uint(x);
  return (unsigned short)((u + 0x7FFFu + ((u >> 16) & 1u)) >> 16);
}
__device__ __forceinline__ float bf2f(unsigned short h) {
  return __uint_as_float(((unsigned int)h) << 16);
}

// DPP helpers (VALU pipe).
__device__ __forceinline__ float qxor1(float x) {
  return __int_as_float(__builtin_amdgcn_update_dpp(
      0, __float_as_int(x), 0xB1, 0xF, 0xF, true));
}
__device__ __forceinline__ float qxor2(float x) {
  return __int_as_float(__builtin_amdgcn_update_dpp(
      0, __float_as_int(x), 0x4E, 0xF, 0xF, true));
}
__device__ __forceinline__ float hmirror(float x) {  // row_half_mirror
  return __int_as_float(__builtin_amdgcn_update_dpp(
      0, __float_as_int(x), 0x141, 0xF, 0xF, true));
}
// All-VALU butterfly sum over the 8-lane group. Groups are 8-lane-aligned and
// share c, so exec-masked use is safe (all 8 lanes active together).
__device__ __forceinline__ float groupSum8(float x) {
  x += qxor1(x);
  x += qxor2(x);
  x += hmirror(x);
  return x;
}

// slarfg sign convention (LAPACK); fast rcp/sqrt (R17-validated).
__device__ __forceinline__ void make_tau(float xn2, float alpha, float& tau,
                                         float& invs) {
  if (xn2 == 0.f) { tau = 0.f; invs = 0.f; }
  else {
    float mag = fsqrt_fast(fmaf(alpha, alpha, xn2));
    float beta = (alpha >= 0.f) ? -mag : mag;
    tau = (beta - alpha) * frcp(beta);
    invs = frcp(alpha - beta);
  }
}

__device__ __forceinline__ float pk_dot8(const f32x2 (&x)[8],
                                         const f32x2 (&y)[8]) {
  f32x2 pa = {0.f, 0.f}, pb = {0.f, 0.f};
#pragma unroll
  for (int i = 0; i < 4; ++i) {
    pa = pkfma(x[2 * i], y[2 * i], pa);
    pb = pkfma(x[2 * i + 1], y[2 * i + 1], pb);
  }
  return (pa.x + pa.y) + (pb.x + pb.y);
}

__device__ __forceinline__ float norm_gt8(const f32x2 (&a2)[8], const int t,
                                          const int piv) {
  float ss[4] = {0.f, 0.f, 0.f, 0.f};
#pragma unroll
  for (int q = 0; q < 4; ++q)
#pragma unroll
    for (int kk = 0; kk < 4; ++kk) {
      int k = 4 * q + kk;
      int r = t + 8 * k;
      float av = a2[k >> 1][k & 1];
      if (r > piv) ss[q] = fmaf(av, av, ss[q]);
    }
  return ((ss[0] + ss[1]) + ss[2]) + ss[3];
}

template <bool SCALE>
__device__ __forceinline__ void publish_col8(f32x2 (&a2)[8], const int t,
                                             const int piv, const float invs,
                                             float* __restrict__ Vrow) {
#pragma unroll
  for (int k4 = 0; k4 < 4; ++k4) {
    float4 v4;
    float* vv = (float*)&v4;
#pragma unroll
    for (int e = 0; e < 4; ++e) {
      int k = 4 * k4 + e;
      int r = t + 8 * k;
      float av = a2[k >> 1][k & 1];
      float nv;
      if (r > piv) {
        if (SCALE) { av *= invs; a2[k >> 1][k & 1] = av; }
        nv = av;
      } else nv = (r == piv) ? 1.f : 0.f;
      vv[e] = nv;
    }
    *(float4*)&Vrow[4 * k4] = v4;
  }
}

__device__ __forceinline__ void load_v8(f32x2 (&vr2)[8],
                                        const float* __restrict__ Vrow) {
#pragma unroll
  for (int k4 = 0; k4 < 4; ++k4) {
    float4 v4 = *(const float4*)&Vrow[4 * k4];
    vr2[2 * k4] = (f32x2){v4.x, v4.y};
    vr2[2 * k4 + 1] = (f32x2){v4.z, v4.w};
  }
}

// ---------------- pre-split kernels (write d_ws; fragment-order layout) -------
__global__ __launch_bounds__(256) void presplit_w(const float* __restrict__ W,
                                                  unsigned short* __restrict__ Wp) {
  int id = blockIdx.x * 256 + threadIdx.x;
  int row = id & 127;
  int fg = (id >> 7) & 3;
  int mc = id >> 9;
  int mm = mc >> 4, ch = mc & 15;
  const float* src = W + ((size_t)mm * DOUT + row) * DIN + ch * 32 + fg * 8;
  bf16x8 hi, lo;
  unsigned short* hp = (unsigned short*)&hi;
  unsigned short* lp = (unsigned short*)&lo;
#pragma unroll
  for (int e = 0; e < 8; ++e) {
    float v = src[e];
    unsigned short h = f2bf(v);
    hp[e] = h;
    lp[e] = f2bf(v - bf2f(h));
  }
  unsigned short* dst = Wp + (size_t)mc * 8192 + (fg * 128 + row) * 8;
  *(bf16x8*)dst = hi;
  *(bf16x8*)(dst + 4096) = lo;
}

__global__ __launch_bounds__(256) void presplit_x(const float* __restrict__ X,
                                                  unsigned short* __restrict__ Xp) {
  int id = blockIdx.x * 256 + threadIdx.x;
  int col = id & 63;
  int fg = (id >> 6) & 3;
  int bc = id >> 8;
  int bb = bc >> 4, ch = bc & 15;
  const float* src = X + ((size_t)bb * DIN + ch * 32 + fg * 8) * QD + col;
  bf16x8 hi, lo;
  unsigned short* hp = (unsigned short*)&hi;
  unsigned short* lp = (unsigned short*)&lo;
#pragma unroll
  for (int e = 0; e < 8; ++e) {
    float v = src[(size_t)e * QD];
    unsigned short h = f2bf(v);
    hp[e] = h;
    lp[e] = f2bf(v - bf2f(h));
  }
  unsigned short* dst = Xp + (size_t)bc * 4096 + (fg * 64 + col) * 8;
  *(bf16x8*)dst = hi;
  *(bf16x8*)(dst + 2048) = lo;
}

// Union: Buf (handoff/store) aliases Vall (persistent V). Alias fences at the
// two phase transitions. (R14 proved this union correct; its perf failure was
// register spill from 8-wide batching, not the union.)
union USh {
  float Buf[64][68];    // 17408 B
  float Vall[QD][160];  // 40960 B; v_j at Vall[j][t*TST + k], banks cover all 32
};

// One block (512 thr = 8 waves) per matrix (m,b).
// 2a: R17 sequential sgeqr2 (1 barrier/step, publish-ahead) into persistent Vall.
// 2b: BARRIER-FREE. All reflectors static after 2a. Formation hoisted (column c
//   is idle in steps i > c), then per-wave uniform loop i = 8w+6..0 predicated
//   c > i: every active lane reads the SAME V_i (broadcast, conflict-free —
//   avoids R11's divergent-column conflicts). Bitwise-identical per-column op
//   sequence to R17's 2b.
template <bool PRE>
__global__ __launch_bounds__(512, 6) void frmap_qr(
    const float* __restrict__ X, const float* __restrict__ W,
    float* __restrict__ out, const unsigned short* __restrict__ Wp,
    const unsigned short* __restrict__ Xp) {
  __shared__ __align__(16) USh U;
  __shared__ float Tau[QD];

  const int tid = threadIdx.x;
  const int l = tid & 63;
  const int w = __builtin_amdgcn_readfirstlane(tid >> 6);  // wave 0..7
  const int rg = w >> 1;  // GEMM row-group
  const int cg = w & 1;   // GEMM col-group
  const int c = tid >> 3; // QR column 0..63
  const int t = tid & 7;  // QR row class (rows t+8k)
  const int fr = l & 15;
  const int fg = l >> 4;

  const int bid = blockIdx.x;  // m*256 + b
  const int m = bid >> 8;
  const int b = bid & 255;
  const float* Xb = X + (size_t)b * (DIN * QD);
  const float* Wm = W + (size_t)m * (DOUT * DIN);

  f32x4 acc[2][2];
#pragma unroll
  for (int tr = 0; tr < 2; ++tr)
#pragma unroll
    for (int tc = 0; tc < 2; ++tc)
      acc[tr][tc] = (f32x4){0.f, 0.f, 0.f, 0.f};

  if constexpr (PRE) {
    const char* wsrc = (const char*)Wp + (size_t)(m * 16) * 16384;
    const char* xsrc = (const char*)Xp + (size_t)(b * 16) * 8192;
    const int woff = (fg * 128 + 32 * rg + fr) * 16;
    const int xoff = (fg * 64 + 32 * cg + fr) * 16;
    for (int ch = 0; ch < 16; ++ch) {
      bf16x8 ah0 = *(const bf16x8*)(wsrc + woff);
      bf16x8 al0 = *(const bf16x8*)(wsrc + 8192 + woff);
      bf16x8 ah1 = *(const bf16x8*)(wsrc + woff + 256);
      bf16x8 al1 = *(const bf16x8*)(wsrc + 8192 + woff + 256);
      bf16x8 bh0 = *(const bf16x8*)(xsrc + xoff);
      bf16x8 bl0 = *(const bf16x8*)(xsrc + 4096 + xoff);
      bf16x8 bh1 = *(const bf16x8*)(xsrc + xoff + 256);
      bf16x8 bl1 = *(const bf16x8*)(xsrc + 4096 + xoff + 256);
      acc[0][0] = __builtin_amdgcn_mfma_f32_16x16x32_bf16(ah0, bh0, acc[0][0], 0, 0, 0);
      acc[0][0] = __builtin_amdgcn_mfma_f32_16x16x32_bf16(ah0, bl0, acc[0][0], 0, 0, 0);
      acc[0][0] = __builtin_amdgcn_mfma_f32_16x16x32_bf16(al0, bh0, acc[0][0], 0, 0, 0);
      acc[0][1] = __builtin_amdgcn_mfma_f32_16x16x32_bf16(ah0, bh1, acc[0][1], 0, 0, 0);
      acc[0][1] = __builtin_amdgcn_mfma_f32_16x16x32_bf16(ah0, bl1, acc[0][1], 0, 0, 0);
      acc[0][1] = __builtin_amdgcn_mfma_f32_16x16x32_bf16(al0, bh1, acc[0][1], 0, 0, 0);
      acc[1][0] = __builtin_amdgcn_mfma_f32_16x16x32_bf16(ah1, bh0, acc[1][0], 0, 0, 0);
      acc[1][0] = __builtin_amdgcn_mfma_f32_16x16x32_bf16(ah1, bl0, acc[1][0], 0, 0, 0);
      acc[1][0] = __builtin_amdgcn_mfma_f32_16x16x32_bf16(al1, bh0, acc[1][0], 0, 0, 0);
      acc[1][1] = __builtin_amdgcn_mfma_f32_16x16x32_bf16(ah1, bh1, acc[1][1], 0, 0, 0);
      acc[1][1] = __builtin_amdgcn_mfma_f32_16x16x32_bf16(ah1, bl1, acc[1][1], 0, 0, 0);
      acc[1][1] = __builtin_amdgcn_mfma_f32_16x16x32_bf16(al1, bh1, acc[1][1], 0, 0, 0);
      wsrc += 16384;
      xsrc += 8192;
    }
  } else {
    for (int ch = 0; ch < 16; ++ch) {
      int kc = ch * 32;
      bf16x8 ah[2], al[2], bh[2], bl[2];
#pragma unroll
      for (int tr = 0; tr < 2; ++tr) {
        const float* ws = Wm + (size_t)(32 * rg + 16 * tr + fr) * DIN + kc + 8 * fg;
        float4 v0 = *(const float4*)ws;
        float4 v1 = *(const float4*)(ws + 4);
        float p[8] = {v0.x, v0.y, v0.z, v0.w, v1.x, v1.y, v1.z, v1.w};
        unsigned short* hp = (unsigned short*)&ah[tr];
        unsigned short* lp = (unsigned short*)&al[tr];
#pragma unroll
        for (int e = 0; e < 8; ++e) {
          unsigned short h = f2bf(p[e]);
          hp[e] = h;
          lp[e] = f2bf(p[e] - bf2f(h));
        }
      }
#pragma unroll
      for (int tc = 0; tc < 2; ++tc) {
        const float* xs = Xb + (size_t)(kc + 8 * fg) * QD + 32 * cg + 16 * tc + fr;
        unsigned short* hp = (unsigned short*)&bh[tc];
        unsigned short* lp = (unsigned short*)&bl[tc];
#pragma unroll
        for (int e = 0; e < 8; ++e) {
          float v = xs[(size_t)e * QD];
          unsigned short h = f2bf(v);
          hp[e] = h;
          lp[e] = f2bf(v - bf2f(h));
        }
      }
#pragma unroll
      for (int tr = 0; tr < 2; ++tr)
#pragma unroll
        for (int tc = 0; tc < 2; ++tc) {
          acc[tr][tc] = __builtin_amdgcn_mfma_f32_16x16x32_bf16(ah[tr], bh[tc], acc[tr][tc], 0, 0, 0);
          acc[tr][tc] = __builtin_amdgcn_mfma_f32_16x16x32_bf16(ah[tr], bl[tc], acc[tr][tc], 0, 0, 0);
          acc[tr][tc] = __builtin_amdgcn_mfma_f32_16x16x32_bf16(al[tr], bh[tc], acc[tr][tc], 0, 0, 0);
        }
    }
  }

  // ---------------- Phase 1.5: acc -> Buf -> QR ownership
  f32x2 a2[8];
  if (rg < 2) {
#pragma unroll
    for (int tr = 0; tr < 2; ++tr)
#pragma unroll
      for (int tc = 0; tc < 2; ++tc)
#pragma unroll
        for (int v = 0; v < 4; ++v)
          U.Buf[32 * rg + 16 * tr + 4 * fg + v][32 * cg + 16 * tc + fr] = acc[tr][tc][v];
  }
  __syncthreads();
#pragma unroll
  for (int k = 0; k < 8; ++k) a2[k >> 1][k & 1] = U.Buf[t + 8 * k][c];
  __syncthreads();
  if (rg >= 2) {
#pragma unroll
    for (int tr = 0; tr < 2; ++tr)
#pragma unroll
      for (int tc = 0; tc < 2; ++tc)
#pragma unroll
        for (int v = 0; v < 4; ++v)
          U.Buf[32 * (rg - 2) + 16 * tr + 4 * fg + v][32 * cg + 16 * tc + fr] = acc[tr][tc][v];
  }
  __syncthreads();
#pragma unroll
  for (int k = 8; k < 16; ++k) a2[k >> 1][k & 1] = U.Buf[t + 8 * k - 64][c];
  __syncthreads();  // ALIAS FENCE: Buf reads done before Vall (union) writes

  // ---------------- prologue: group c==0 makes tau0/invs0, scales, publishes
  if (c == 0) {
    float myalpha = 0.f;
#pragma unroll
    for (int k = 0; k < 16; ++k)
      if (t + 8 * k == 0) myalpha = a2[k >> 1][k & 1];
    float xn2 = groupSum8(norm_gt8(a2, t, 0));
    float alpha = groupSum8(myalpha);
    float tau, invs;
    make_tau(xn2, alpha, tau, invs);
    if (t == 0) Tau[0] = tau;
    publish_col8<true>(a2, t, 0, invs, &U.Vall[0][t * TST]);
  }
  __syncthreads();  // B0: V_0 / Tau[0] visible

  // ---------------- Phase 2a: sgeqr2 (1 barrier/step, publish-ahead)
  for (int j = 0; j < QD - 1; ++j) {
    if (c > j) {
      float taul = Tau[j];
      f32x2 vr2[8];
      load_v8(vr2, &U.Vall[j][t * TST]);  // uniform col -> broadcast
      float wv = taul * groupSum8(pk_dot8(vr2, a2));
      f32x2 nw2 = {-wv, -wv};
#pragma unroll
      for (int i = 0; i < 8; ++i) a2[i] = pkfma(nw2, vr2[i], a2[i]);
      if (c == j + 1) {  // tail: next pivot's tau/scale/publish
        float myalpha = 0.f;
#pragma unroll
        for (int k = 0; k < 16; ++k)
          if (t + 8 * k == j + 1) myalpha = a2[k >> 1][k & 1];
        float xn2 = groupSum8(norm_gt8(a2, t, j + 1));
        float alpha = groupSum8(myalpha);
        float tau, invs;
        make_tau(xn2, alpha, tau, invs);
        if (t == 0) Tau[j + 1] = tau;
        publish_col8<true>(a2, t, j + 1, invs, &U.Vall[j + 1][t * TST]);
      }
    }
    __syncthreads();  // fences V_{j+1}, Tau[j+1]
  }
  // After j=62's barrier, all of Vall[0..63] and Tau[0..63] are visible.

  // ---------------- Phase 2b: BARRIER-FREE per-wave backward apply
  {
    float tauc = Tau[c];
#pragma unroll
    for (int k = 0; k < 16; ++k) {  // formation: u = e_c - tau_c v_c (hoisted;
      int r = t + 8 * k;            // column c is idle during steps i > c)
      float val = a2[k >> 1][k & 1];
      float nv;
      if (r == c) nv = 1.f - tauc;
      else if (r < c) nv = 0.f;
      else nv = -tauc * val;
      a2[k >> 1][k & 1] = nv;
    }
    const int itop = __builtin_amdgcn_readfirstlane(8 * w + 6);  // wave-uniform
    for (int i = itop; i >= 0; --i) {
      if (c > i) {  // all active lanes read the SAME column: broadcast
        float taul = Tau[i];
        f32x2 vr2[8];
        load_v8(vr2, &U.Vall[i][t * TST]);
        float wv = taul * groupSum8(pk_dot8(vr2, a2));
        f32x2 nw2 = {-wv, -wv};
#pragma unroll
        for (int q = 0; q < 8; ++q) a2[q] = pkfma(nw2, vr2[q], a2[q]);
      }
    }
  }
  __syncthreads();  // ALIAS FENCE: all Vall reads done before Buf (union) writes

  // ---------------- Phase 3: store via Buf (256B-coalesced)
  float* O = out + (size_t)bid * (DOUT * QD);
#pragma unroll
  for (int k = 0; k < 8; ++k) U.Buf[t + 8 * k][c] = a2[k >> 1][k & 1];
  __syncthreads();
#pragma unroll
  for (int i = 0; i < 8; ++i) {
    int r = 8 * w + i;
    O[r * QD + l] = U.Buf[r][l];
  }
  __syncthreads();
#pragma unroll
  for (int k = 8; k < 16; ++k) U.Buf[t + 8 * k - 64][c] = a2[k >> 1][k & 1];
  __syncthreads();
#pragma unroll
  for (int i = 0; i < 8; ++i) {
    int r = 8 * w + i;
    O[(64 + r) * QD + l] = U.Buf[r][l];
  }
}

extern "C" void kernel_launch(void* const* d_in, const int* in_sizes, int n_in,
                              void* d_out, int out_size, void* d_ws, size_t ws_size,
                              hipStream_t stream) {
  const float* X = (const float*)d_in[0];   // (256, 512, 64) fp32
  const float* W = (const float*)d_in[1];   // (16, 128, 512) fp32
  float* out = (float*)d_out;               // (4096, 128, 64) fp32

  const size_t needW = (size_t)NMAPS * 16 * 16384;  // 4 MiB
  const size_t needX = (size_t)256 * 16 * 8192;     // 32 MiB
  if (ws_size >= needW + needX) {
    unsigned short* Wp = (unsigned short*)d_ws;
    unsigned short* Xp = (unsigned short*)((char*)d_ws + needW);
    presplit_w<<<512, 256, 0, stream>>>(W, Wp);
    presplit_x<<<4096, 256, 0, stream>>>(X, Xp);
    frmap_qr<true><<<NMAPS * 256, 512, 0, stream>>>(X, W, out, Wp, Xp);
  } else {
    frmap_qr<false><<<NMAPS * 256, 512, 0, stream>>>(X, W, out, nullptr, nullptr);
  }
}

// Round 19
// 325.752 us; speedup vs baseline: 3.9401x; 1.0906x over previous
//
#include <hip/hip_runtime.h>
#include <math.h>

#define NMAPS 16
#define DIN 512
#define DOUT 128
#define QD 64
#define TST 16   // per-t sub-stride in a V column (8x16 = 128 floats/col).
                 // Banks: (16t+4k4)%32 -> t and t+2 alias = 2-way conflict,
                 // which is FREE on CDNA4 (m136: 1.02x). Saves 8KB/block vs
                 // TST=20 -> LDS 41.5->33KB -> 4 blocks/CU (was 3).

typedef __attribute__((ext_vector_type(8))) short bf16x8;  // 8 bf16 (4 VGPR)
typedef __attribute__((ext_vector_type(4))) float f32x4;
typedef __attribute__((ext_vector_type(2))) float f32x2;

// Packed fp32 FMA (VOP3P): bitwise-identical to two scalar fmaf's.
__device__ __forceinline__ f32x2 pkfma(f32x2 a, f32x2 b, f32x2 c) {
  f32x2 d;
  asm("v_pk_fma_f32 %0, %1, %2, %3" : "=v"(d) : "v"(a), "v"(b), "v"(c));
  return d;
}

// Fast scalar ops (~1 ulp), validated R17.
__device__ __forceinline__ float frcp(float x) {
  float r;
  asm("v_rcp_f32 %0, %1" : "=v"(r) : "v"(x));
  return r;
}
__device__ __forceinline__ float fsqrt_fast(float x) {
  float r;
  asm("v_sqrt_f32 %0, %1" : "=v"(r) : "v"(x));
  return r;
}

// bf16 split helpers (RNE). x = bf2f(hi) + bf2f(lo) + O(2^-18 |x|).
__device__ __forceinline__ unsigned short f2bf(float x) {
  unsigned int u = __float_as_uint(x);
  return (unsigned short)((u + 0x7FFFu + ((u >> 16) & 1u)) >> 16);
}
__device__ __forceinline__ float bf2f(unsigned short h) {
  return __uint_as_float(((unsigned int)h) << 16);
}

// DPP helpers (VALU pipe).
__device__ __forceinline__ float qxor1(float x) {
  return __int_as_float(__builtin_amdgcn_update_dpp(
      0, __float_as_int(x), 0xB1, 0xF, 0xF, true));
}
__device__ __forceinline__ float qxor2(float x) {
  return __int_as_float(__builtin_amdgcn_update_dpp(
      0, __float_as_int(x), 0x4E, 0xF, 0xF, true));
}
__device__ __forceinline__ float hmirror(float x) {  // row_half_mirror
  return __int_as_float(__builtin_amdgcn_update_dpp(
      0, __float_as_int(x), 0x141, 0xF, 0xF, true));
}
// All-VALU butterfly sum over the 8-lane group (R13-validated).
__device__ __forceinline__ float groupSum8(float x) {
  x += qxor1(x);
  x += qxor2(x);
  x += hmirror(x);
  return x;
}

// slarfg sign convention (LAPACK); fast rcp/sqrt (R17-validated).
__device__ __forceinline__ void make_tau(float xn2, float alpha, float& tau,
                                         float& invs) {
  if (xn2 == 0.f) { tau = 0.f; invs = 0.f; }
  else {
    float mag = fsqrt_fast(fmaf(alpha, alpha, xn2));
    float beta = (alpha >= 0.f) ? -mag : mag;
    tau = (beta - alpha) * frcp(beta);
    invs = frcp(alpha - beta);
  }
}

__device__ __forceinline__ float pk_dot8(const f32x2 (&x)[8],
                                         const f32x2 (&y)[8]) {
  f32x2 pa = {0.f, 0.f}, pb = {0.f, 0.f};
#pragma unroll
  for (int i = 0; i < 4; ++i) {
    pa = pkfma(x[2 * i], y[2 * i], pa);
    pb = pkfma(x[2 * i + 1], y[2 * i + 1], pb);
  }
  return (pa.x + pa.y) + (pb.x + pb.y);
}

__device__ __forceinline__ float norm_gt8(const f32x2 (&a2)[8], const int t,
                                          const int piv) {
  float ss[4] = {0.f, 0.f, 0.f, 0.f};
#pragma unroll
  for (int q = 0; q < 4; ++q)
#pragma unroll
    for (int kk = 0; kk < 4; ++kk) {
      int k = 4 * q + kk;
      int r = t + 8 * k;
      float av = a2[k >> 1][k & 1];
      if (r > piv) ss[q] = fmaf(av, av, ss[q]);
    }
  return ((ss[0] + ss[1]) + ss[2]) + ss[3];
}

template <bool SCALE>
__device__ __forceinline__ void publish_col8(f32x2 (&a2)[8], const int t,
                                             const int piv, const float invs,
                                             float* __restrict__ Vrow) {
#pragma unroll
  for (int k4 = 0; k4 < 4; ++k4) {
    float4 v4;
    float* vv = (float*)&v4;
#pragma unroll
    for (int e = 0; e < 4; ++e) {
      int k = 4 * k4 + e;
      int r = t + 8 * k;
      float av = a2[k >> 1][k & 1];
      float nv;
      if (r > piv) {
        if (SCALE) { av *= invs; a2[k >> 1][k & 1] = av; }
        nv = av;
      } else nv = (r == piv) ? 1.f : 0.f;
      vv[e] = nv;
    }
    *(float4*)&Vrow[4 * k4] = v4;
  }
}

__device__ __forceinline__ void load_v8(f32x2 (&vr2)[8],
                                        const float* __restrict__ Vrow) {
#pragma unroll
  for (int k4 = 0; k4 < 4; ++k4) {
    float4 v4 = *(const float4*)&Vrow[4 * k4];
    vr2[2 * k4] = (f32x2){v4.x, v4.y};
    vr2[2 * k4 + 1] = (f32x2){v4.z, v4.w};
  }
}

// ---------------- pre-split kernels (write d_ws; fragment-order layout) -------
__global__ __launch_bounds__(256) void presplit_w(const float* __restrict__ W,
                                                  unsigned short* __restrict__ Wp) {
  int id = blockIdx.x * 256 + threadIdx.x;
  int row = id & 127;
  int fg = (id >> 7) & 3;
  int mc = id >> 9;
  int mm = mc >> 4, ch = mc & 15;
  const float* src = W + ((size_t)mm * DOUT + row) * DIN + ch * 32 + fg * 8;
  bf16x8 hi, lo;
  unsigned short* hp = (unsigned short*)&hi;
  unsigned short* lp = (unsigned short*)&lo;
#pragma unroll
  for (int e = 0; e < 8; ++e) {
    float v = src[e];
    unsigned short h = f2bf(v);
    hp[e] = h;
    lp[e] = f2bf(v - bf2f(h));
  }
  unsigned short* dst = Wp + (size_t)mc * 8192 + (fg * 128 + row) * 8;
  *(bf16x8*)dst = hi;
  *(bf16x8*)(dst + 4096) = lo;
}

__global__ __launch_bounds__(256) void presplit_x(const float* __restrict__ X,
                                                  unsigned short* __restrict__ Xp) {
  int id = blockIdx.x * 256 + threadIdx.x;
  int col = id & 63;
  int fg = (id >> 6) & 3;
  int bc = id >> 8;
  int bb = bc >> 4, ch = bc & 15;
  const float* src = X + ((size_t)bb * DIN + ch * 32 + fg * 8) * QD + col;
  bf16x8 hi, lo;
  unsigned short* hp = (unsigned short*)&hi;
  unsigned short* lp = (unsigned short*)&lo;
#pragma unroll
  for (int e = 0; e < 8; ++e) {
    float v = src[(size_t)e * QD];
    unsigned short h = f2bf(v);
    hp[e] = h;
    lp[e] = f2bf(v - bf2f(h));
  }
  unsigned short* dst = Xp + (size_t)bc * 4096 + (fg * 64 + col) * 8;
  *(bf16x8*)dst = hi;
  *(bf16x8*)(dst + 2048) = lo;
}

// Union: Buf (handoff/store) aliases Vall (persistent V); alias fences at the
// phase transitions. Vall now unpadded [64][128] (2-way conflicts = free).
union USh {
  float Buf[64][68];    // 17408 B
  float Vall[QD][128];  // 32768 B; v_j at Vall[j][t*TST + k]
};

// One block (512 thr = 8 waves) per matrix (m,b). R18 structure:
// 2a sequential sgeqr2 (1 barrier/step, publish-ahead, fast-math tail);
// 2b barrier-free per-wave backward apply (uniform-column broadcast reads).
template <bool PRE>
__global__ __launch_bounds__(512, 6) void frmap_qr(
    const float* __restrict__ X, const float* __restrict__ W,
    float* __restrict__ out, const unsigned short* __restrict__ Wp,
    const unsigned short* __restrict__ Xp) {
  __shared__ __align__(16) USh U;
  __shared__ float Tau[QD];

  const int tid = threadIdx.x;
  const int l = tid & 63;
  const int w = __builtin_amdgcn_readfirstlane(tid >> 6);  // wave 0..7
  const int rg = w >> 1;  // GEMM row-group
  const int cg = w & 1;   // GEMM col-group
  const int c = tid >> 3; // QR column 0..63
  const int t = tid & 7;  // QR row class (rows t+8k)
  const int fr = l & 15;
  const int fg = l >> 4;

  const int bid = blockIdx.x;  // m*256 + b
  const int m = bid >> 8;
  const int b = bid & 255;
  const float* Xb = X + (size_t)b * (DIN * QD);
  const float* Wm = W + (size_t)m * (DOUT * DIN);

  f32x4 acc[2][2];
#pragma unroll
  for (int tr = 0; tr < 2; ++tr)
#pragma unroll
    for (int tc = 0; tc < 2; ++tc)
      acc[tr][tc] = (f32x4){0.f, 0.f, 0.f, 0.f};

  if constexpr (PRE) {
    const char* wsrc = (const char*)Wp + (size_t)(m * 16) * 16384;
    const char* xsrc = (const char*)Xp + (size_t)(b * 16) * 8192;
    const int woff = (fg * 128 + 32 * rg + fr) * 16;
    const int xoff = (fg * 64 + 32 * cg + fr) * 16;
    for (int ch = 0; ch < 16; ++ch) {
      bf16x8 ah0 = *(const bf16x8*)(wsrc + woff);
      bf16x8 al0 = *(const bf16x8*)(wsrc + 8192 + woff);
      bf16x8 ah1 = *(const bf16x8*)(wsrc + woff + 256);
      bf16x8 al1 = *(const bf16x8*)(wsrc + 8192 + woff + 256);
      bf16x8 bh0 = *(const bf16x8*)(xsrc + xoff);
      bf16x8 bl0 = *(const bf16x8*)(xsrc + 4096 + xoff);
      bf16x8 bh1 = *(const bf16x8*)(xsrc + xoff + 256);
      bf16x8 bl1 = *(const bf16x8*)(xsrc + 4096 + xoff + 256);
      acc[0][0] = __builtin_amdgcn_mfma_f32_16x16x32_bf16(ah0, bh0, acc[0][0], 0, 0, 0);
      acc[0][0] = __builtin_amdgcn_mfma_f32_16x16x32_bf16(ah0, bl0, acc[0][0], 0, 0, 0);
      acc[0][0] = __builtin_amdgcn_mfma_f32_16x16x32_bf16(al0, bh0, acc[0][0], 0, 0, 0);
      acc[0][1] = __builtin_amdgcn_mfma_f32_16x16x32_bf16(ah0, bh1, acc[0][1], 0, 0, 0);
      acc[0][1] = __builtin_amdgcn_mfma_f32_16x16x32_bf16(ah0, bl1, acc[0][1], 0, 0, 0);
      acc[0][1] = __builtin_amdgcn_mfma_f32_16x16x32_bf16(al0, bh1, acc[0][1], 0, 0, 0);
      acc[1][0] = __builtin_amdgcn_mfma_f32_16x16x32_bf16(ah1, bh0, acc[1][0], 0, 0, 0);
      acc[1][0] = __builtin_amdgcn_mfma_f32_16x16x32_bf16(ah1, bl0, acc[1][0], 0, 0, 0);
      acc[1][0] = __builtin_amdgcn_mfma_f32_16x16x32_bf16(al1, bh0, acc[1][0], 0, 0, 0);
      acc[1][1] = __builtin_amdgcn_mfma_f32_16x16x32_bf16(ah1, bh1, acc[1][1], 0, 0, 0);
      acc[1][1] = __builtin_amdgcn_mfma_f32_16x16x32_bf16(ah1, bl1, acc[1][1], 0, 0, 0);
      acc[1][1] = __builtin_amdgcn_mfma_f32_16x16x32_bf16(al1, bh1, acc[1][1], 0, 0, 0);
      wsrc += 16384;
      xsrc += 8192;
    }
  } else {
    for (int ch = 0; ch < 16; ++ch) {
      int kc = ch * 32;
      bf16x8 ah[2], al[2], bh[2], bl[2];
#pragma unroll
      for (int tr = 0; tr < 2; ++tr) {
        const float* ws = Wm + (size_t)(32 * rg + 16 * tr + fr) * DIN + kc + 8 * fg;
        float4 v0 = *(const float4*)ws;
        float4 v1 = *(const float4*)(ws + 4);
        float p[8] = {v0.x, v0.y, v0.z, v0.w, v1.x, v1.y, v1.z, v1.w};
        unsigned short* hp = (unsigned short*)&ah[tr];
        unsigned short* lp = (unsigned short*)&al[tr];
#pragma unroll
        for (int e = 0; e < 8; ++e) {
          unsigned short h = f2bf(p[e]);
          hp[e] = h;
          lp[e] = f2bf(p[e] - bf2f(h));
        }
      }
#pragma unroll
      for (int tc = 0; tc < 2; ++tc) {
        const float* xs = Xb + (size_t)(kc + 8 * fg) * QD + 32 * cg + 16 * tc + fr;
        unsigned short* hp = (unsigned short*)&bh[tc];
        unsigned short* lp = (unsigned short*)&bl[tc];
#pragma unroll
        for (int e = 0; e < 8; ++e) {
          float v = xs[(size_t)e * QD];
          unsigned short h = f2bf(v);
          hp[e] = h;
          lp[e] = f2bf(v - bf2f(h));
        }
      }
#pragma unroll
      for (int tr = 0; tr < 2; ++tr)
#pragma unroll
        for (int tc = 0; tc < 2; ++tc) {
          acc[tr][tc] = __builtin_amdgcn_mfma_f32_16x16x32_bf16(ah[tr], bh[tc], acc[tr][tc], 0, 0, 0);
          acc[tr][tc] = __builtin_amdgcn_mfma_f32_16x16x32_bf16(ah[tr], bl[tc], acc[tr][tc], 0, 0, 0);
          acc[tr][tc] = __builtin_amdgcn_mfma_f32_16x16x32_bf16(al[tr], bh[tc], acc[tr][tc], 0, 0, 0);
        }
    }
  }

  // ---------------- Phase 1.5: acc -> Buf -> QR ownership
  f32x2 a2[8];
  if (rg < 2) {
#pragma unroll
    for (int tr = 0; tr < 2; ++tr)
#pragma unroll
      for (int tc = 0; tc < 2; ++tc)
#pragma unroll
        for (int v = 0; v < 4; ++v)
          U.Buf[32 * rg + 16 * tr + 4 * fg + v][32 * cg + 16 * tc + fr] = acc[tr][tc][v];
  }
  __syncthreads();
#pragma unroll
  for (int k = 0; k < 8; ++k) a2[k >> 1][k & 1] = U.Buf[t + 8 * k][c];
  __syncthreads();
  if (rg >= 2) {
#pragma unroll
    for (int tr = 0; tr < 2; ++tr)
#pragma unroll
      for (int tc = 0; tc < 2; ++tc)
#pragma unroll
        for (int v = 0; v < 4; ++v)
          U.Buf[32 * (rg - 2) + 16 * tr + 4 * fg + v][32 * cg + 16 * tc + fr] = acc[tr][tc][v];
  }
  __syncthreads();
#pragma unroll
  for (int k = 8; k < 16; ++k) a2[k >> 1][k & 1] = U.Buf[t + 8 * k - 64][c];
  __syncthreads();  // ALIAS FENCE: Buf reads done before Vall (union) writes

  // ---------------- prologue: group c==0 makes tau0/invs0, scales, publishes
  if (c == 0) {
    float myalpha = 0.f;
#pragma unroll
    for (int k = 0; k < 16; ++k)
      if (t + 8 * k == 0) myalpha = a2[k >> 1][k & 1];
    float xn2 = groupSum8(norm_gt8(a2, t, 0));
    float alpha = groupSum8(myalpha);
    float tau, invs;
    make_tau(xn2, alpha, tau, invs);
    if (t == 0) Tau[0] = tau;
    publish_col8<true>(a2, t, 0, invs, &U.Vall[0][t * TST]);
  }
  __syncthreads();  // B0: V_0 / Tau[0] visible

  // ---------------- Phase 2a: sgeqr2 (1 barrier/step, publish-ahead)
  for (int j = 0; j < QD - 1; ++j) {
    if (c > j) {
      float taul = Tau[j];
      f32x2 vr2[8];
      load_v8(vr2, &U.Vall[j][t * TST]);  // uniform col -> broadcast
      float wv = taul * groupSum8(pk_dot8(vr2, a2));
      f32x2 nw2 = {-wv, -wv};
#pragma unroll
      for (int i = 0; i < 8; ++i) a2[i] = pkfma(nw2, vr2[i], a2[i]);
      if (c == j + 1) {  // tail: next pivot's tau/scale/publish
        float myalpha = 0.f;
#pragma unroll
        for (int k = 0; k < 16; ++k)
          if (t + 8 * k == j + 1) myalpha = a2[k >> 1][k & 1];
        float xn2 = groupSum8(norm_gt8(a2, t, j + 1));
        float alpha = groupSum8(myalpha);
        float tau, invs;
        make_tau(xn2, alpha, tau, invs);
        if (t == 0) Tau[j + 1] = tau;
        publish_col8<true>(a2, t, j + 1, invs, &U.Vall[j + 1][t * TST]);
      }
    }
    __syncthreads();  // fences V_{j+1}, Tau[j+1]
  }
  // After j=62's barrier, all of Vall[0..63] and Tau[0..63] are visible.

  // ---------------- Phase 2b: BARRIER-FREE per-wave backward apply
  {
    float tauc = Tau[c];
#pragma unroll
    for (int k = 0; k < 16; ++k) {  // formation: u = e_c - tau_c v_c (hoisted)
      int r = t + 8 * k;
      float val = a2[k >> 1][k & 1];
      float nv;
      if (r == c) nv = 1.f - tauc;
      else if (r < c) nv = 0.f;
      else nv = -tauc * val;
      a2[k >> 1][k & 1] = nv;
    }
    const int itop = __builtin_amdgcn_readfirstlane(8 * w + 6);  // wave-uniform
    for (int i = itop; i >= 0; --i) {
      if (c > i) {  // all active lanes read the SAME column: broadcast
        float taul = Tau[i];
        f32x2 vr2[8];
        load_v8(vr2, &U.Vall[i][t * TST]);
        float wv = taul * groupSum8(pk_dot8(vr2, a2));
        f32x2 nw2 = {-wv, -wv};
#pragma unroll
        for (int q = 0; q < 8; ++q) a2[q] = pkfma(nw2, vr2[q], a2[q]);
      }
    }
  }
  __syncthreads();  // ALIAS FENCE: all Vall reads done before Buf (union) writes

  // ---------------- Phase 3: store via Buf (256B-coalesced)
  float* O = out + (size_t)bid * (DOUT * QD);
#pragma unroll
  for (int k = 0; k < 8; ++k) U.Buf[t + 8 * k][c] = a2[k >> 1][k & 1];
  __syncthreads();
#pragma unroll
  for (int i = 0; i < 8; ++i) {
    int r = 8 * w + i;
    O[r * QD + l] = U.Buf[r][l];
  }
  __syncthreads();
#pragma unroll
  for (int k = 8; k < 16; ++k) U.Buf[t + 8 * k - 64][c] = a2[k >> 1][k & 1];
  __syncthreads();
#pragma unroll
  for (int i = 0; i < 8; ++i) {
    int r = 8 * w + i;
    O[(64 + r) * QD + l] = U.Buf[r][l];
  }
}

extern "C" void kernel_launch(void* const* d_in, const int* in_sizes, int n_in,
                              void* d_out, int out_size, void* d_ws, size_t ws_size,
                              hipStream_t stream) {
  const float* X = (const float*)d_in[0];   // (256, 512, 64) fp32
  const float* W = (const float*)d_in[1];   // (16, 128, 512) fp32
  float* out = (float*)d_out;               // (4096, 128, 64) fp32

  const size_t needW = (size_t)NMAPS * 16 * 16384;  // 4 MiB
  const size_t needX = (size_t)256 * 16 * 8192;     // 32 MiB
  if (ws_size >= needW + needX) {
    unsigned short* Wp = (unsigned short*)d_ws;
    unsigned short* Xp = (unsigned short*)((char*)d_ws + needW);
    presplit_w<<<512, 256, 0, stream>>>(W, Wp);
    presplit_x<<<4096, 256, 0, stream>>>(X, Xp);
    frmap_qr<true><<<NMAPS * 256, 512, 0, stream>>>(X, W, out, Wp, Xp);
  } else {
    frmap_qr<false><<<NMAPS * 256, 512, 0, stream>>>(X, W, out, nullptr, nullptr);
  }
}

// Round 20
// 323.692 us; speedup vs baseline: 3.9652x; 1.0064x over previous
//
#include <hip/hip_runtime.h>
#include <math.h>

#define NMAPS 16
#define DIN 512
#define DOUT 128
#define QD 64
#define TST 16   // per-t sub-stride in a V column (8x16 = 128 floats/col).
                 // 2-way bank aliasing = free on CDNA4 (m136: 1.02x).

typedef __attribute__((ext_vector_type(8))) short bf16x8;  // 8 bf16 (4 VGPR)
typedef __attribute__((ext_vector_type(4))) float f32x4;
typedef __attribute__((ext_vector_type(2))) float f32x2;

// Packed fp32 FMA (VOP3P): bitwise-identical to two scalar fmaf's.
__device__ __forceinline__ f32x2 pkfma(f32x2 a, f32x2 b, f32x2 c) {
  f32x2 d;
  asm("v_pk_fma_f32 %0, %1, %2, %3" : "=v"(d) : "v"(a), "v"(b), "v"(c));
  return d;
}

// Fast scalar ops (~1 ulp), validated R17.
__device__ __forceinline__ float frcp(float x) {
  float r;
  asm("v_rcp_f32 %0, %1" : "=v"(r) : "v"(x));
  return r;
}
__device__ __forceinline__ float fsqrt_fast(float x) {
  float r;
  asm("v_sqrt_f32 %0, %1" : "=v"(r) : "v"(x));
  return r;
}

// bf16 split helpers (RNE). x = bf2f(hi) + bf2f(lo) + O(2^-18 |x|).
__device__ __forceinline__ unsigned short f2bf(float x) {
  unsigned int u = __float_as_uint(x);
  return (unsigned short)((u + 0x7FFFu + ((u >> 16) & 1u)) >> 16);
}
__device__ __forceinline__ float bf2f(unsigned short h) {
  return __uint_as_float(((unsigned int)h) << 16);
}

// DPP helpers (VALU pipe).
__device__ __forceinline__ float qxor1(float x) {
  return __int_as_float(__builtin_amdgcn_update_dpp(
      0, __float_as_int(x), 0xB1, 0xF, 0xF, true));
}
__device__ __forceinline__ float qxor2(float x) {
  return __int_as_float(__builtin_amdgcn_update_dpp(
      0, __float_as_int(x), 0x4E, 0xF, 0xF, true));
}
__device__ __forceinline__ float hmirror(float x) {  // row_half_mirror
  return __int_as_float(__builtin_amdgcn_update_dpp(
      0, __float_as_int(x), 0x141, 0xF, 0xF, true));
}
// All-VALU butterfly sum over the 8-lane group (R13-validated).
__device__ __forceinline__ float groupSum8(float x) {
  x += qxor1(x);
  x += qxor2(x);
  x += hmirror(x);
  return x;
}

// slarfg sign convention (LAPACK); fast rcp/sqrt (R17-validated).
__device__ __forceinline__ void make_tau(float xn2, float alpha, float& tau,
                                         float& invs) {
  if (xn2 == 0.f) { tau = 0.f; invs = 0.f; }
  else {
    float mag = fsqrt_fast(fmaf(alpha, alpha, xn2));
    float beta = (alpha >= 0.f) ? -mag : mag;
    tau = (beta - alpha) * frcp(beta);
    invs = frcp(alpha - beta);
  }
}

__device__ __forceinline__ float pk_dot8(const f32x2 (&x)[8],
                                         const f32x2 (&y)[8]) {
  f32x2 pa = {0.f, 0.f}, pb = {0.f, 0.f};
#pragma unroll
  for (int i = 0; i < 4; ++i) {
    pa = pkfma(x[2 * i], y[2 * i], pa);
    pb = pkfma(x[2 * i + 1], y[2 * i + 1], pb);
  }
  return (pa.x + pa.y) + (pb.x + pb.y);
}

__device__ __forceinline__ float norm_gt8(const f32x2 (&a2)[8], const int t,
                                          const int piv) {
  float ss[4] = {0.f, 0.f, 0.f, 0.f};
#pragma unroll
  for (int q = 0; q < 4; ++q)
#pragma unroll
    for (int kk = 0; kk < 4; ++kk) {
      int k = 4 * q + kk;
      int r = t + 8 * k;
      float av = a2[k >> 1][k & 1];
      if (r > piv) ss[q] = fmaf(av, av, ss[q]);
    }
  return ((ss[0] + ss[1]) + ss[2]) + ss[3];
}

template <bool SCALE>
__device__ __forceinline__ void publish_col8(f32x2 (&a2)[8], const int t,
                                             const int piv, const float invs,
                                             float* __restrict__ Vrow) {
#pragma unroll
  for (int k4 = 0; k4 < 4; ++k4) {
    float4 v4;
    float* vv = (float*)&v4;
#pragma unroll
    for (int e = 0; e < 4; ++e) {
      int k = 4 * k4 + e;
      int r = t + 8 * k;
      float av = a2[k >> 1][k & 1];
      float nv;
      if (r > piv) {
        if (SCALE) { av *= invs; a2[k >> 1][k & 1] = av; }
        nv = av;
      } else nv = (r == piv) ? 1.f : 0.f;
      vv[e] = nv;
    }
    *(float4*)&Vrow[4 * k4] = v4;
  }
}

__device__ __forceinline__ void load_v8(f32x2 (&vr2)[8],
                                        const float* __restrict__ Vrow) {
#pragma unroll
  for (int k4 = 0; k4 < 4; ++k4) {
    float4 v4 = *(const float4*)&Vrow[4 * k4];
    vr2[2 * k4] = (f32x2){v4.x, v4.y};
    vr2[2 * k4 + 1] = (f32x2){v4.z, v4.w};
  }
}

// ---------------- pre-split kernels (write d_ws; fragment-order layout) -------
__global__ __launch_bounds__(256) void presplit_w(const float* __restrict__ W,
                                                  unsigned short* __restrict__ Wp) {
  int id = blockIdx.x * 256 + threadIdx.x;
  int row = id & 127;
  int fg = (id >> 7) & 3;
  int mc = id >> 9;
  int mm = mc >> 4, ch = mc & 15;
  const float* src = W + ((size_t)mm * DOUT + row) * DIN + ch * 32 + fg * 8;
  bf16x8 hi, lo;
  unsigned short* hp = (unsigned short*)&hi;
  unsigned short* lp = (unsigned short*)&lo;
#pragma unroll
  for (int e = 0; e < 8; ++e) {
    float v = src[e];
    unsigned short h = f2bf(v);
    hp[e] = h;
    lp[e] = f2bf(v - bf2f(h));
  }
  unsigned short* dst = Wp + (size_t)mc * 8192 + (fg * 128 + row) * 8;
  *(bf16x8*)dst = hi;
  *(bf16x8*)(dst + 4096) = lo;
}

__global__ __launch_bounds__(256) void presplit_x(const float* __restrict__ X,
                                                  unsigned short* __restrict__ Xp) {
  int id = blockIdx.x * 256 + threadIdx.x;
  int col = id & 63;
  int fg = (id >> 6) & 3;
  int bc = id >> 8;
  int bb = bc >> 4, ch = bc & 15;
  const float* src = X + ((size_t)bb * DIN + ch * 32 + fg * 8) * QD + col;
  bf16x8 hi, lo;
  unsigned short* hp = (unsigned short*)&hi;
  unsigned short* lp = (unsigned short*)&lo;
#pragma unroll
  for (int e = 0; e < 8; ++e) {
    float v = src[(size_t)e * QD];
    unsigned short h = f2bf(v);
    hp[e] = h;
    lp[e] = f2bf(v - bf2f(h));
  }
  unsigned short* dst = Xp + (size_t)bc * 4096 + (fg * 64 + col) * 8;
  *(bf16x8*)dst = hi;
  *(bf16x8*)(dst + 2048) = lo;
}

// Union: FULL-HEIGHT Buf[128][68] (34816 B) aliases Vall[64][128] (32768 B).
// Single-pass handoff and store (was 2 half-height passes with 4 barriers
// each). Banks: writes (16fg+fr)%32 2-way; reads (4t+c)%32 2-way; store-reads
// l%32 2-way — all free (m136). LDS 35072 B x 4 blocks = 140K <= 160K.
union USh {
  float Buf[128][68];   // 34816 B
  float Vall[QD][128];  // 32768 B; v_j at Vall[j][t*TST + k]
};

// One block (512 thr = 8 waves) per matrix (m,b). R19 structure:
// 2a sequential sgeqr2 (1 barrier/step, publish-ahead, fast-math tail);
// 2b barrier-free per-wave backward apply (uniform-column broadcast reads);
// single-pass handoff/store via full-height Buf.
template <bool PRE>
__global__ __launch_bounds__(512, 6) void frmap_qr(
    const float* __restrict__ X, const float* __restrict__ W,
    float* __restrict__ out, const unsigned short* __restrict__ Wp,
    const unsigned short* __restrict__ Xp) {
  __shared__ __align__(16) USh U;
  __shared__ float Tau[QD];

  const int tid = threadIdx.x;
  const int l = tid & 63;
  const int w = __builtin_amdgcn_readfirstlane(tid >> 6);  // wave 0..7
  const int rg = w >> 1;  // GEMM row-group
  const int cg = w & 1;   // GEMM col-group
  const int c = tid >> 3; // QR column 0..63
  const int t = tid & 7;  // QR row class (rows t+8k)
  const int fr = l & 15;
  const int fg = l >> 4;

  const int bid = blockIdx.x;  // m*256 + b
  const int m = bid >> 8;
  const int b = bid & 255;
  const float* Xb = X + (size_t)b * (DIN * QD);
  const float* Wm = W + (size_t)m * (DOUT * DIN);

  f32x4 acc[2][2];
#pragma unroll
  for (int tr = 0; tr < 2; ++tr)
#pragma unroll
    for (int tc = 0; tc < 2; ++tc)
      acc[tr][tc] = (f32x4){0.f, 0.f, 0.f, 0.f};

  if constexpr (PRE) {
    const char* wsrc = (const char*)Wp + (size_t)(m * 16) * 16384;
    const char* xsrc = (const char*)Xp + (size_t)(b * 16) * 8192;
    const int woff = (fg * 128 + 32 * rg + fr) * 16;
    const int xoff = (fg * 64 + 32 * cg + fr) * 16;
    for (int ch = 0; ch < 16; ++ch) {
      bf16x8 ah0 = *(const bf16x8*)(wsrc + woff);
      bf16x8 al0 = *(const bf16x8*)(wsrc + 8192 + woff);
      bf16x8 ah1 = *(const bf16x8*)(wsrc + woff + 256);
      bf16x8 al1 = *(const bf16x8*)(wsrc + 8192 + woff + 256);
      bf16x8 bh0 = *(const bf16x8*)(xsrc + xoff);
      bf16x8 bl0 = *(const bf16x8*)(xsrc + 4096 + xoff);
      bf16x8 bh1 = *(const bf16x8*)(xsrc + xoff + 256);
      bf16x8 bl1 = *(const bf16x8*)(xsrc + 4096 + xoff + 256);
      acc[0][0] = __builtin_amdgcn_mfma_f32_16x16x32_bf16(ah0, bh0, acc[0][0], 0, 0, 0);
      acc[0][0] = __builtin_amdgcn_mfma_f32_16x16x32_bf16(ah0, bl0, acc[0][0], 0, 0, 0);
      acc[0][0] = __builtin_amdgcn_mfma_f32_16x16x32_bf16(al0, bh0, acc[0][0], 0, 0, 0);
      acc[0][1] = __builtin_amdgcn_mfma_f32_16x16x32_bf16(ah0, bh1, acc[0][1], 0, 0, 0);
      acc[0][1] = __builtin_amdgcn_mfma_f32_16x16x32_bf16(ah0, bl1, acc[0][1], 0, 0, 0);
      acc[0][1] = __builtin_amdgcn_mfma_f32_16x16x32_bf16(al0, bh1, acc[0][1], 0, 0, 0);
      acc[1][0] = __builtin_amdgcn_mfma_f32_16x16x32_bf16(ah1, bh0, acc[1][0], 0, 0, 0);
      acc[1][0] = __builtin_amdgcn_mfma_f32_16x16x32_bf16(ah1, bl0, acc[1][0], 0, 0, 0);
      acc[1][0] = __builtin_amdgcn_mfma_f32_16x16x32_bf16(al1, bh0, acc[1][0], 0, 0, 0);
      acc[1][1] = __builtin_amdgcn_mfma_f32_16x16x32_bf16(ah1, bh1, acc[1][1], 0, 0, 0);
      acc[1][1] = __builtin_amdgcn_mfma_f32_16x16x32_bf16(ah1, bl1, acc[1][1], 0, 0, 0);
      acc[1][1] = __builtin_amdgcn_mfma_f32_16x16x32_bf16(al1, bh1, acc[1][1], 0, 0, 0);
      wsrc += 16384;
      xsrc += 8192;
    }
  } else {
    for (int ch = 0; ch < 16; ++ch) {
      int kc = ch * 32;
      bf16x8 ah[2], al[2], bh[2], bl[2];
#pragma unroll
      for (int tr = 0; tr < 2; ++tr) {
        const float* ws = Wm + (size_t)(32 * rg + 16 * tr + fr) * DIN + kc + 8 * fg;
        float4 v0 = *(const float4*)ws;
        float4 v1 = *(const float4*)(ws + 4);
        float p[8] = {v0.x, v0.y, v0.z, v0.w, v1.x, v1.y, v1.z, v1.w};
        unsigned short* hp = (unsigned short*)&ah[tr];
        unsigned short* lp = (unsigned short*)&al[tr];
#pragma unroll
        for (int e = 0; e < 8; ++e) {
          unsigned short h = f2bf(p[e]);
          hp[e] = h;
          lp[e] = f2bf(p[e] - bf2f(h));
        }
      }
#pragma unroll
      for (int tc = 0; tc < 2; ++tc) {
        const float* xs = Xb + (size_t)(kc + 8 * fg) * QD + 32 * cg + 16 * tc + fr;
        unsigned short* hp = (unsigned short*)&bh[tc];
        unsigned short* lp = (unsigned short*)&bl[tc];
#pragma unroll
        for (int e = 0; e < 8; ++e) {
          float v = xs[(size_t)e * QD];
          unsigned short h = f2bf(v);
          hp[e] = h;
          lp[e] = f2bf(v - bf2f(h));
        }
      }
#pragma unroll
      for (int tr = 0; tr < 2; ++tr)
#pragma unroll
        for (int tc = 0; tc < 2; ++tc) {
          acc[tr][tc] = __builtin_amdgcn_mfma_f32_16x16x32_bf16(ah[tr], bh[tc], acc[tr][tc], 0, 0, 0);
          acc[tr][tc] = __builtin_amdgcn_mfma_f32_16x16x32_bf16(ah[tr], bl[tc], acc[tr][tc], 0, 0, 0);
          acc[tr][tc] = __builtin_amdgcn_mfma_f32_16x16x32_bf16(al[tr], bh[tc], acc[tr][tc], 0, 0, 0);
        }
    }
  }

  // ---------------- Phase 1.5: acc -> Buf (single pass, full height) -> a2
  // C/D layout (m89): row = 32rg + 16tr + 4fg + reg, col = 32cg + 16tc + fr.
  f32x2 a2[8];
#pragma unroll
  for (int tr = 0; tr < 2; ++tr)
#pragma unroll
    for (int tc = 0; tc < 2; ++tc)
#pragma unroll
      for (int v = 0; v < 4; ++v)
        U.Buf[32 * rg + 16 * tr + 4 * fg + v][32 * cg + 16 * tc + fr] = acc[tr][tc][v];
  __syncthreads();
#pragma unroll
  for (int k = 0; k < 16; ++k) a2[k >> 1][k & 1] = U.Buf[t + 8 * k][c];
  __syncthreads();  // ALIAS FENCE: Buf reads done before Vall (union) writes

  // ---------------- prologue: group c==0 makes tau0/invs0, scales, publishes
  if (c == 0) {
    float myalpha = 0.f;
#pragma unroll
    for (int k = 0; k < 16; ++k)
      if (t + 8 * k == 0) myalpha = a2[k >> 1][k & 1];
    float xn2 = groupSum8(norm_gt8(a2, t, 0));
    float alpha = groupSum8(myalpha);
    float tau, invs;
    make_tau(xn2, alpha, tau, invs);
    if (t == 0) Tau[0] = tau;
    publish_col8<true>(a2, t, 0, invs, &U.Vall[0][t * TST]);
  }
  __syncthreads();  // B0: V_0 / Tau[0] visible

  // ---------------- Phase 2a: sgeqr2 (1 barrier/step, publish-ahead)
  for (int j = 0; j < QD - 1; ++j) {
    if (c > j) {
      float taul = Tau[j];
      f32x2 vr2[8];
      load_v8(vr2, &U.Vall[j][t * TST]);  // uniform col -> broadcast
      float wv = taul * groupSum8(pk_dot8(vr2, a2));
      f32x2 nw2 = {-wv, -wv};
#pragma unroll
      for (int i = 0; i < 8; ++i) a2[i] = pkfma(nw2, vr2[i], a2[i]);
      if (c == j + 1) {  // tail: next pivot's tau/scale/publish
        float myalpha = 0.f;
#pragma unroll
        for (int k = 0; k < 16; ++k)
          if (t + 8 * k == j + 1) myalpha = a2[k >> 1][k & 1];
        float xn2 = groupSum8(norm_gt8(a2, t, j + 1));
        float alpha = groupSum8(myalpha);
        float tau, invs;
        make_tau(xn2, alpha, tau, invs);
        if (t == 0) Tau[j + 1] = tau;
        publish_col8<true>(a2, t, j + 1, invs, &U.Vall[j + 1][t * TST]);
      }
    }
    __syncthreads();  // fences V_{j+1}, Tau[j+1]
  }
  // After j=62's barrier, all of Vall[0..63] and Tau[0..63] are visible.

  // ---------------- Phase 2b: BARRIER-FREE per-wave backward apply
  {
    float tauc = Tau[c];
#pragma unroll
    for (int k = 0; k < 16; ++k) {  // formation: u = e_c - tau_c v_c (hoisted)
      int r = t + 8 * k;
      float val = a2[k >> 1][k & 1];
      float nv;
      if (r == c) nv = 1.f - tauc;
      else if (r < c) nv = 0.f;
      else nv = -tauc * val;
      a2[k >> 1][k & 1] = nv;
    }
    const int itop = __builtin_amdgcn_readfirstlane(8 * w + 6);  // wave-uniform
    for (int i = itop; i >= 0; --i) {
      if (c > i) {  // all active lanes read the SAME column: broadcast
        float taul = Tau[i];
        f32x2 vr2[8];
        load_v8(vr2, &U.Vall[i][t * TST]);
        float wv = taul * groupSum8(pk_dot8(vr2, a2));
        f32x2 nw2 = {-wv, -wv};
#pragma unroll
        for (int q = 0; q < 8; ++q) a2[q] = pkfma(nw2, vr2[q], a2[q]);
      }
    }
  }
  __syncthreads();  // ALIAS FENCE: all Vall reads done before Buf (union) writes

  // ---------------- Phase 3: store via full-height Buf (single pass)
  float* O = out + (size_t)bid * (DOUT * QD);
#pragma unroll
  for (int k = 0; k < 16; ++k) U.Buf[t + 8 * k][c] = a2[k >> 1][k & 1];
  __syncthreads();
#pragma unroll
  for (int i = 0; i < 16; ++i) {
    int r = 16 * w + i;     // 8 waves x 16 rows = 128 rows, 256B-coalesced
    O[r * QD + l] = U.Buf[r][l];
  }
}

extern "C" void kernel_launch(void* const* d_in, const int* in_sizes, int n_in,
                              void* d_out, int out_size, void* d_ws, size_t ws_size,
                              hipStream_t stream) {
  const float* X = (const float*)d_in[0];   // (256, 512, 64) fp32
  const float* W = (const float*)d_in[1];   // (16, 128, 512) fp32
  float* out = (float*)d_out;               // (4096, 128, 64) fp32

  const size_t needW = (size_t)NMAPS * 16 * 16384;  // 4 MiB
  const size_t needX = (size_t)256 * 16 * 8192;     // 32 MiB
  if (ws_size >= needW + needX) {
    unsigned short* Wp = (unsigned short*)d_ws;
    unsigned short* Xp = (unsigned short*)((char*)d_ws + needW);
    presplit_w<<<512, 256, 0, stream>>>(W, Wp);
    presplit_x<<<4096, 256, 0, stream>>>(X, Xp);
    frmap_qr<true><<<NMAPS * 256, 512, 0, stream>>>(X, W, out, Wp, Xp);
  } else {
    frmap_qr<false><<<NMAPS * 256, 512, 0, stream>>>(X, W, out, nullptr, nullptr);
  }
}